// Round 5
// baseline (2141.952 us; speedup 1.0000x reference)
//
#include <hip/hip_runtime.h>
#include <hip/hip_cooperative_groups.h>
#include <math.h>

namespace cg = cooperative_groups;

#define NBATCH 512
#define NDIM 256
#define NHID 512
#define NC 32
#define NTAIL 30
#define NP 64
#define TEV 16
#define MAXIT 10
#define TOLF 0.01f
#define PI_F 3.14159265358979323846f

typedef __bf16 bf16_t;
typedef __bf16 bf16x8 __attribute__((ext_vector_type(8)));
typedef float f32x4 __attribute__((ext_vector_type(4)));
typedef unsigned short ushort_t;

// ---- workspace layout (float slots) ----
constexpr size_t OFF_TCHEB = 0;        // 64
constexpr size_t OFF_PHIT  = 64;       // 2048
constexpr size_t OFF_PD2I  = 2112;     // 64
constexpr size_t OFF_M2    = 2176;     // 64
constexpr size_t OFF_INV0  = 2240;     // 16
constexpr size_t OFF_PHIOUT= 2256;     // 512
constexpr size_t OFF_PQ    = 2768;     // 2048 (setup scratch)
constexpr size_t OFF_PQBH  = 4816;     // [32][64] bf16 hi (1024 floats)
constexpr size_t OFF_PQBL  = 5840;     // 1024
constexpr size_t OFF_PHIH  = 6864;     // [64][32] bf16 hi of Phi (A-layout), 1024 floats
constexpr size_t OFF_PHIL  = 7888;     // 1024
constexpr size_t OFF_SCAL  = 8912;     // accum double [0:1], done [2], counter [3]  (fallback path)
constexpr size_t OFF_H1F   = 8928;
constexpr size_t OFF_YF2I  = OFF_H1F + 262144;
constexpr size_t OFF_YM2   = OFF_YF2I + 262144;
constexpr size_t OFF_BT    = OFF_YM2 + 3932160;
constexpr size_t OFF_W1T   = OFF_BT + 3932160;    // [512][256] bf16
constexpr size_t OFF_W2T   = OFF_W1T + 65536;     // [256][512] bf16
constexpr size_t OFF_ACC   = OFF_W2T + 65536;     // 16 doubles: per-iteration delta^2 accumulators
constexpr size_t WS_FLOATS = OFF_ACC + 32;

// ---- output layout (floats) ----
constexpr size_t OUT_TEVAL = 0;
constexpr size_t OUT_TRAJ  = 16;
constexpr size_t OUT_DELTA = 16 + (size_t)TEV*NBATCH*NDIM;
constexpr size_t OUT_B     = OUT_DELTA + 1;

__device__ __forceinline__ ushort_t bf16bits(float v) {
    bf16_t h = (bf16_t)v; ushort_t u; __builtin_memcpy(&u, &h, 2); return u;
}
__device__ __forceinline__ float bf16val(ushort_t u) {
    bf16_t h; __builtin_memcpy(&h, &u, 2); return (float)h;
}

// ============ setup: spectral operators (round-2/6 proven fp64 parallel GJ) ============
__global__ void setup_kernel(const float* __restrict__ t_eval, float* __restrict__ ws,
                             float* __restrict__ out)
{
    __shared__ float Phi[32][64];
    __shared__ float DPhi[32][64];
    __shared__ float Phib[30][64];
    __shared__ float tcs[64];
    __shared__ float DtS[64];
    __shared__ float inv0s[4];
    __shared__ float pd2s[30][2];
    __shared__ double Gaug[30][61];
    __shared__ double rowk[60];
    __shared__ double colk[30];

    const int tid = threadIdx.x;
    const float t0 = t_eval[0], t1 = t_eval[TEV-1];
    const float sgn = (t1 > t0) ? 1.f : -1.f;

    if (tid < 64) {
        const float t = -sgn * cosf(PI_F * (float)tid / 64.f);
        tcs[tid] = t;
        float p0 = 1.f, p1 = t;
        Phi[0][tid] = p0; Phi[1][tid] = p1;
        for (int k = 2; k < 32; ++k) { float pk = 2.f*t*p1 - p0; Phi[k][tid] = pk; p0 = p1; p1 = pk; }
        const float sc = 2.f / (t1 - t0);
        float u0 = 1.f, u1 = 2.f*t;
        DPhi[0][tid] = 0.f;
        DPhi[1][tid] = sc * 1.f * u0;
        DPhi[2][tid] = sc * 2.f * u1;
        for (int k = 3; k < 32; ++k) { float uk = 2.f*t*u1 - u0; DPhi[k][tid] = sc * (float)k * uk; u0 = u1; u1 = uk; }
    }
    __syncthreads();
    if (tid < 64) DtS[tid] = ((tid < 63) ? tcs[tid+1] : 1.0f) - tcs[tid];
    if (tid == 0) {
        double a = Phi[0][0], b = DPhi[0][0], c = Phi[1][0], d = DPhi[1][0];
        double det = a*d - b*c;
        inv0s[0] = (float)( d/det); inv0s[1] = (float)(-b/det);
        inv0s[2] = (float)(-c/det); inv0s[3] = (float)( a/det);
    }
    __syncthreads();
    if (tid == 0) { ws[OFF_INV0+0]=inv0s[0]; ws[OFF_INV0+1]=inv0s[1]; ws[OFF_INV0+2]=inv0s[2]; ws[OFF_INV0+3]=inv0s[3]; }
    if (tid < 30) {
        float P = Phi[2+tid][0], D = DPhi[2+tid][0];
        float a0 = P*inv0s[0] + D*inv0s[2];
        float a1 = P*inv0s[1] + D*inv0s[3];
        pd2s[tid][0] = a0; pd2s[tid][1] = a1;
        ws[OFF_PD2I + tid*2+0] = a0;
        ws[OFF_PD2I + tid*2+1] = a1;
    }
    __syncthreads();
    if (tid < 64)
        for (int m = 0; m < 30; ++m)
            Phib[m][tid] = DPhi[2+m][tid] - (pd2s[m][0]*DPhi[0][tid] + pd2s[m][1]*DPhi[1][tid]);
    __syncthreads();

    for (int e = tid; e < 900; e += 256) {
        int i = e / 30, j = e % 30;
        double s = 0.0;
        for (int p = 0; p < 64; ++p) s += (double)Phib[i][p] * (double)DtS[p] * (double)Phib[j][p];
        Gaug[i][j] = s;
        Gaug[i][30+j] = (i == j) ? 1.0 : 0.0;
    }
    __syncthreads();

    for (int k = 0; k < 30; ++k) {
        double invpv = 1.0 / Gaug[k][k];
        if (tid < 60) rowk[tid] = Gaug[k][tid] * invpv;
        if (tid >= 64 && tid < 94) colk[tid-64] = Gaug[tid-64][k];
        __syncthreads();
        for (int e = tid; e < 1800; e += 256) {
            int i = e / 60, j = e - i*60;
            if (i == k) Gaug[i][j] = rowk[j];
            else        Gaug[i][j] -= colk[i] * rowk[j];
        }
        __syncthreads();
    }

    if (tid < 64) {
        ushort_t* pqh = (ushort_t*)(ws + OFF_PQBH);
        ushort_t* pql = (ushort_t*)(ws + OFF_PQBL);
        float pqrow[32];
        for (int n = 0; n < 30; ++n) {
            double s = 0.0;
            for (int m = 0; m < 30; ++m) s += (double)Phib[m][tid] * Gaug[m][30+n];
            pqrow[n] = (float)((double)DtS[tid] * s);
        }
        pqrow[30] = 0.f; pqrow[31] = 0.f;
        for (int n = 0; n < 32; ++n) {
            ws[OFF_PQ + (size_t)tid*32 + n] = pqrow[n];
            bf16_t h = (bf16_t)pqrow[n];
            float hf = (float)h;
            pqh[n*64 + tid] = bf16bits(pqrow[n]);
            pql[n*64 + tid] = bf16bits(pqrow[n] - hf);
        }
    }
    __syncthreads();

    if (tid < 30) {
        double a20 = 0.0, a21 = 0.0;
        for (int p = 0; p < 64; ++p) {
            double pq = (double)ws[OFF_PQ + (size_t)p*32 + tid];
            a20 += (double)DPhi[0][p] * pq;
            a21 += (double)DPhi[1][p] * pq;
        }
        ws[OFF_M2 + 0*32 + tid] = (float)((double)inv0s[0]*a20 + (double)inv0s[1]*a21);
        ws[OFF_M2 + 1*32 + tid] = (float)((double)inv0s[2]*a20 + (double)inv0s[3]*a21);
    }

    if (tid < 64) {
        ushort_t* phh = (ushort_t*)(ws + OFF_PHIH);
        ushort_t* phl = (ushort_t*)(ws + OFF_PHIL);
        for (int n = 0; n < 32; ++n) {
            float f = Phi[n][tid];
            ws[OFF_PHIT + (size_t)tid*32 + n] = f;
            ushort_t hb = bf16bits(f);
            phh[tid*32 + n] = hb;
            phl[tid*32 + n] = bf16bits(f - bf16val(hb));
        }
        ws[OFF_TCHEB + tid] = tcs[tid];
    }

    if (tid < TEV) {
        float te = t_eval[tid];
        out[OUT_TEVAL + tid] = te;
        float tt = -1.f + 2.f*(te - t0)/(t1 - t0);
        float q0 = 1.f, q1 = tt;
        ws[OFF_PHIOUT + (size_t)tid*32 + 0] = q0;
        ws[OFF_PHIOUT + (size_t)tid*32 + 1] = q1;
        for (int k = 2; k < 32; ++k) { float qk = 2.f*tt*q1 - q0; ws[OFF_PHIOUT + (size_t)tid*32 + k] = qk; q0 = q1; q1 = qk; }
    }

    if (tid == 0) {
        double* acc = (double*)(ws + OFF_SCAL);
        acc[0] = 0.0;
        int* ip = (int*)(ws + OFF_SCAL + 2);
        ip[0] = 0;  // done
        ip[1] = 0;  // counter
    }
    if (tid < 16) ((double*)(ws + OFF_ACC))[tid] = 0.0;   // per-iteration accumulators
}

// ============ B_init [b][d][n] -> Bt [b][n][d] ============
__global__ __launch_bounds__(256) void transB_kernel(const float* __restrict__ Bin, float* __restrict__ Bt)
{
    const int t = threadIdx.x, b = blockIdx.x;
    const float* src = Bin + ((size_t)(b*NDIM + t)) * NTAIL;
    #pragma unroll
    for (int n = 0; n < NTAIL; ++n)
        Bt[((size_t)b*NTAIL + n)*NDIM + t] = src[n];
}

// ============ W [R][C] f32 -> Wt [C][R] bf16 ============
__global__ __launch_bounds__(256) void transW_kernel(const float* __restrict__ W, bf16_t* __restrict__ Wt,
                                                     int R, int C)
{
    __shared__ float Ls[64][65];
    const int r0 = blockIdx.x*64, c0 = blockIdx.y*64;
    const int lr = threadIdx.x >> 6, lc = threadIdx.x & 63;
    #pragma unroll
    for (int i = 0; i < 16; ++i) {
        int rr = i*4 + lr;
        Ls[rr][lc] = W[(size_t)(r0+rr)*C + c0+lc];
    }
    __syncthreads();
    #pragma unroll
    for (int i = 0; i < 16; ++i) {
        int cc = i*4 + lr;
        Wt[(size_t)(c0+cc)*R + r0 + lc] = (bf16_t)Ls[lc][cc];
    }
}

// ============ f_init ============
__global__ __launch_bounds__(512) void finit_h_kernel(const float* __restrict__ y, const float* __restrict__ W1,
                                                      const float* __restrict__ b1, const float* __restrict__ t_eval,
                                                      float* __restrict__ h1)
{
    __shared__ float ys[NDIM];
    const int t = threadIdx.x, b = blockIdx.x;
    if (t < NDIM) ys[t] = y[(size_t)b*NDIM + t];
    __syncthreads();
    float acc = b1[t] + t_eval[0];
    for (int d = 0; d < NDIM; ++d) acc += ys[d] * W1[(size_t)d*NHID + t];
    h1[(size_t)b*NHID + t] = tanhf(acc);
}

__global__ __launch_bounds__(256) void finit_rest_kernel(const float* __restrict__ y, const float* __restrict__ W2,
                                                         const float* __restrict__ b2, const float* __restrict__ h1,
                                                         const float* __restrict__ inv0, const float* __restrict__ M2,
                                                         float* __restrict__ yf2i, float* __restrict__ yM2)
{
    __shared__ float hs[NHID];
    const int t = threadIdx.x, b = blockIdx.x;
    hs[t] = h1[(size_t)b*NHID + t];
    hs[t+256] = h1[(size_t)b*NHID + 256 + t];
    __syncthreads();
    float f = b2[t];
    for (int h = 0; h < NHID; ++h) f += hs[h] * W2[(size_t)h*NDIM + t];
    const float yv = y[(size_t)b*NDIM + t];
    yf2i[((size_t)b*2 + 0)*NDIM + t] = yv*inv0[0] + f*inv0[2];
    yf2i[((size_t)b*2 + 1)*NDIM + t] = yv*inv0[1] + f*inv0[3];
    #pragma unroll
    for (int n = 0; n < NTAIL; ++n)
        yM2[((size_t)b*NTAIL + n)*NDIM + t] = yv*M2[n] + f*M2[32 + n];
}

// ============ persistent cooperative iteration kernel ============
// Round-11: r2's proven 61 µs/iter body VERBATIM, wrapped in a 10-iteration
// device loop with cg::grid.sync() replacing the 10 kernel boundaries.
// Savings: 9 launch gaps, 10x PQ/constant LDS staging (hoisted before loop),
// 10x trailing done-flag machinery, and the epilogue dispatch (folded in —
// each block owns its batch, no cross-block dependency).
// Co-residency: 512 blocks x 512 thr, 61 KB LDS -> exactly 2 blocks/CU;
// __launch_bounds__(512,4) caps VGPR at 128 so residency is guaranteed.
__global__ __launch_bounds__(512, 4) void iter_persist(
    const float* __restrict__ pd2i, const float* __restrict__ yf2i, const float* __restrict__ tch,
    const bf16_t* __restrict__ W1t, const bf16_t* __restrict__ W2t,
    const float* __restrict__ b1f, const float* __restrict__ b2f,
    const ushort_t* __restrict__ PQhi, const ushort_t* __restrict__ PQlo,
    const ushort_t* __restrict__ phiH, const ushort_t* __restrict__ phiL,
    const float* __restrict__ yM2, float* __restrict__ Bt,
    double* __restrict__ accArr, float* __restrict__ outDelta,
    const float* __restrict__ PhiOut, float* __restrict__ outTraj, float* __restrict__ outB)
{
    cg::grid_group grid = cg::this_grid();

    __shared__ float pd2s[32][2];
    __shared__ float tchS[64];
    __shared__ double redd[8];
    __shared__ __align__(16) char smemA[33792];  // BfT hi/lo -> Ay [64][264]us -> FsT [256][33]u32
    __shared__ __align__(16) char smemB[17408];  // Hc [64][136]us ; Po after loop
    __shared__ __align__(16) ushort_t PQHs[32*72];
    __shared__ __align__(16) ushort_t PQLs[32*72];

    const int t = threadIdx.x;
    const int b = blockIdx.x;            // batch index 0..511
    const int lane = t & 63, w = t >> 6;             // w 0..7
    const int fr = lane & 15, quad = lane >> 4;

    // ---- one-time staging: constants + PQ into LDS ----
    if (t < 60) ((float*)pd2s)[t] = pd2i[t];
    if (t >= 64 && t < 128) tchS[t-64] = tch[t-64];
    if (t >= 256) {
        int e = (t - 256) * 8;           // 256 threads x 8 ushorts = 2048
        int r = e >> 6, c = e & 63;
        uint4 vh = *(const uint4*)(PQhi + e);
        uint4 vl = *(const uint4*)(PQlo + e);
        *(uint4*)(PQHs + r*72 + c) = vh;
        *(uint4*)(PQLs + r*72 + c) = vl;
    }

    float dl = 1e30f;
    for (int it = 0; it < MAXIT; ++it) {
        __syncthreads();   // staging (it=0) / prior-iter smemA reads (it>0) done

        // ---- stage 0a: head coefficients (threads 0..255, t = d), write BfT hi/lo swizzled ----
        if (t < 256) {
            float cf[32];
            #pragma unroll
            for (int n = 0; n < NTAIL; ++n) cf[2+n] = Bt[((size_t)b*NTAIL + n)*NDIM + t];
            float c0 = yf2i[((size_t)b*2 + 0)*NDIM + t];
            float c1 = yf2i[((size_t)b*2 + 1)*NDIM + t];
            #pragma unroll
            for (int n = 0; n < NTAIL; ++n) { c0 -= cf[2+n]*pd2s[n][0]; c1 -= cf[2+n]*pd2s[n][1]; }
            cf[0] = c0; cf[1] = c1;
            unsigned* BH32 = (unsigned*)smemA;             // [256][16] u32 (block-swizzled)
            unsigned* BL32 = (unsigned*)(smemA + 16384);
            #pragma unroll
            for (int n2 = 0; n2 < 16; ++n2) {
                float f0 = cf[2*n2], f1 = cf[2*n2+1];
                ushort_t h0 = bf16bits(f0), h1 = bf16bits(f1);
                ushort_t l0 = bf16bits(f0 - bf16val(h0)), l1 = bf16bits(f1 - bf16val(h1));
                int idx = t*16 + ((n2 >> 2) ^ (t & 3))*4 + (n2 & 3);
                BH32[idx] = (unsigned)h0 | ((unsigned)h1 << 16);
                BL32[idx] = (unsigned)l0 | ((unsigned)l1 << 16);
            }
        }
        __syncthreads();

        // ---- stage 0b: y = Phi @ Bfull via MFMA (hi/lo 3-product), write Ay [64 p][264] bf16 ----
        ushort_t* Ay = (ushort_t*)smemA;
        {
            bf16x8 bH[2], bL[2];
            const ushort_t* BHu = (const ushort_t*)smemA;
            const ushort_t* BLu = (const ushort_t*)(smemA + 16384);
            #pragma unroll
            for (int j = 0; j < 2; ++j) {
                const int d = w*32 + j*16 + fr;
                const int off = d*32 + (quad ^ (d & 3))*8;
                bH[j] = *(const bf16x8*)(BHu + off);
                bL[j] = *(const bf16x8*)(BLu + off);
            }
            bf16x8 aH[4], aL[4];
            #pragma unroll
            for (int i = 0; i < 4; ++i) {
                aH[i] = *(const bf16x8*)(phiH + (i*16 + fr)*32 + quad*8);
                aL[i] = *(const bf16x8*)(phiL + (i*16 + fr)*32 + quad*8);
            }
            __syncthreads();   // all BfT reads done before Ay overwrite
            f32x4 accY[4][2];
            #pragma unroll
            for (int i = 0; i < 4; ++i)
                #pragma unroll
                for (int j = 0; j < 2; ++j) {
                    f32x4 a = (f32x4){0.f,0.f,0.f,0.f};
                    a = __builtin_amdgcn_mfma_f32_16x16x32_bf16(aH[i], bH[j], a, 0, 0, 0);
                    a = __builtin_amdgcn_mfma_f32_16x16x32_bf16(aH[i], bL[j], a, 0, 0, 0);
                    a = __builtin_amdgcn_mfma_f32_16x16x32_bf16(aL[i], bH[j], a, 0, 0, 0);
                    accY[i][j] = a;
                }
            #pragma unroll
            for (int i = 0; i < 4; ++i)
                #pragma unroll
                for (int j = 0; j < 2; ++j)
                    #pragma unroll
                    for (int r = 0; r < 4; ++r) {
                        const int p = i*16 + quad*4 + r;
                        const int d = w*32 + j*16 + fr;
                        Ay[p*264 + d] = bf16bits(accY[i][j][r]);
                    }
        }
        __syncthreads();

        // ---- GEMM1 + tanh + GEMM2 over 4 nh-passes of 128; W2 frags register-prefetched per pass ----
        ushort_t* Hc = (ushort_t*)smemB;     // [64][136]
        f32x4 accF[4][2];                    // rows i*16, d-cols w*32 + j*16
        #pragma unroll
        for (int i = 0; i < 4; ++i)
            #pragma unroll
            for (int j = 0; j < 2; ++j) accF[i][j] = (f32x4){0.f,0.f,0.f,0.f};

        #pragma unroll
        for (int pass = 0; pass < 4; ++pass) {
            // prefetch ALL W2 fragments for this pass; they land during GEMM1's MFMA burst
            bf16x8 w2f[4][2];   // [kt/32][j]
            #pragma unroll
            for (int kt4 = 0; kt4 < 4; ++kt4)
                #pragma unroll
                for (int j = 0; j < 2; ++j) {
                    const int d = w*32 + j*16 + fr;
                    w2f[kt4][j] = *(const bf16x8*)(W2t + (size_t)d*NHID + pass*128 + kt4*32 + quad*8);
                }
            // GEMM1: acc1 = y(64x256) @ W1 chunk (256 x 128); each wave owns 16 h-cols
            f32x4 acc1[4];
            #pragma unroll
            for (int i = 0; i < 4; ++i) acc1[i] = (f32x4){0.f,0.f,0.f,0.f};
            #pragma unroll
            for (int kt = 0; kt < NDIM; kt += 32) {
                bf16x8 af[4], bfv;
                #pragma unroll
                for (int i = 0; i < 4; ++i)
                    af[i] = *(const bf16x8*)(Ay + (i*16 + fr)*264 + kt + quad*8);
                {
                    const int ncol = pass*128 + w*16 + fr;
                    bfv = *(const bf16x8*)(W1t + (size_t)ncol*NDIM + kt + quad*8);
                }
                #pragma unroll
                for (int i = 0; i < 4; ++i)
                    acc1[i] = __builtin_amdgcn_mfma_f32_16x16x32_bf16(af[i], bfv, acc1[i], 0, 0, 0);
            }
            __syncthreads();   // prev pass GEMM2 Hc reads done (also drains w2f loads)
            {
                const int col = w*16 + fr;
                const float bv = b1f[pass*128 + col];
                #pragma unroll
                for (int i = 0; i < 4; ++i)
                    #pragma unroll
                    for (int r = 0; r < 4; ++r) {
                        const int row = i*16 + quad*4 + r;   // = p, 0..63
                        float v = acc1[i][r] + bv + tchS[row];
                        v = fminf(fmaxf(v, -15.f), 15.f);
                        float e = __expf(2.f*v);
                        Hc[row*136 + col] = bf16bits((e - 1.f)/(e + 1.f));
                    }
            }
            __syncthreads();
            // GEMM2 partial: accF += Hc(64x128) @ W2 chunk (128 x 256) — no global loads here
            #pragma unroll
            for (int kt4 = 0; kt4 < 4; ++kt4) {
                bf16x8 af[4];
                #pragma unroll
                for (int i = 0; i < 4; ++i)
                    af[i] = *(const bf16x8*)(Hc + (i*16 + fr)*136 + kt4*32 + quad*8);
                #pragma unroll
                for (int i = 0; i < 4; ++i)
                    #pragma unroll
                    for (int j = 0; j < 2; ++j)
                        accF[i][j] = __builtin_amdgcn_mfma_f32_16x16x32_bf16(af[i], w2f[kt4][j], accF[i][j], 0, 0, 0);
            }
        }
        __syncthreads();   // last GEMM1's Ay reads done; smemA reusable

        // ---- F (+b2) -> FsT [256 d][33] u32 (bf16 row-pairs) ----
        {
            unsigned* FsT32 = (unsigned*)smemA;
            #pragma unroll
            for (int i = 0; i < 4; ++i)
                #pragma unroll
                for (int j = 0; j < 2; ++j) {
                    const int d = w*32 + j*16 + fr;
                    const float bv = b2f[d];
                    #pragma unroll
                    for (int rp = 0; rp < 2; ++rp) {
                        unsigned u0 = bf16bits(accF[i][j][rp*2]   + bv);
                        unsigned u1 = bf16bits(accF[i][j][rp*2+1] + bv);
                        FsT32[d*33 + i*8 + quad*2 + rp] = u0 | (u1 << 16);
                    }
                }
        }
        __syncthreads();

        // ---- PQ contraction: B_new[n][d] = sum_p PQ[n][p]*F[p][d] - yM2, update Bt + norm ----
        double ss = 0.0;
        {
            const ushort_t* FsTu = (const ushort_t*)smemA;
            f32x4 acc2[2][2];
            #pragma unroll
            for (int m2 = 0; m2 < 2; ++m2)
                #pragma unroll
                for (int j2 = 0; j2 < 2; ++j2) acc2[m2][j2] = (f32x4){0.f,0.f,0.f,0.f};
            #pragma unroll
            for (int kk = 0; kk < 2; ++kk) {
                bf16x8 ah[2], al[2];
                #pragma unroll
                for (int m2 = 0; m2 < 2; ++m2) {
                    const int off = (m2*16 + fr)*72 + kk*32 + quad*8;
                    ah[m2] = *(const bf16x8*)(PQHs + off);
                    al[m2] = *(const bf16x8*)(PQLs + off);
                }
                #pragma unroll
                for (int j2 = 0; j2 < 2; ++j2) {
                    const int d2 = w*32 + j2*16 + fr;
                    bf16x8 bfv = *(const bf16x8*)(FsTu + d2*66 + kk*32 + quad*8);
                    #pragma unroll
                    for (int m2 = 0; m2 < 2; ++m2) {
                        acc2[m2][j2] = __builtin_amdgcn_mfma_f32_16x16x32_bf16(ah[m2], bfv, acc2[m2][j2], 0, 0, 0);
                        acc2[m2][j2] = __builtin_amdgcn_mfma_f32_16x16x32_bf16(al[m2], bfv, acc2[m2][j2], 0, 0, 0);
                    }
                }
            }
            #pragma unroll
            for (int m2 = 0; m2 < 2; ++m2)
                #pragma unroll
                for (int j2 = 0; j2 < 2; ++j2)
                    #pragma unroll
                    for (int rr = 0; rr < 4; ++rr) {
                        const int n = m2*16 + quad*4 + rr;
                        if (n < NTAIL) {
                            const int d = w*32 + j2*16 + fr;
                            const size_t idx = ((size_t)b*NTAIL + n)*NDIM + d;
                            float val = acc2[m2][j2][rr] - yM2[idx];
                            float old = Bt[idx];
                            float diff = val - old;
                            Bt[idx] = val;
                            ss += (double)diff*(double)diff;
                        }
                    }
        }

        #pragma unroll
        for (int off = 32; off > 0; off >>= 1) ss += __shfl_down(ss, off, 64);
        if (lane == 0) redd[w] = ss;
        __syncthreads();
        if (t == 0) {
            double tot = redd[0] + redd[1] + redd[2] + redd[3]
                       + redd[4] + redd[5] + redd[6] + redd[7];
            atomicAdd(&accArr[it], tot);
            __threadfence();
        }
        grid.sync();
        double total = *((volatile double*)&accArr[it]);
        dl = (float)sqrt(total);
        if (b == 0 && t == 0) *outDelta = dl;   // last write survives = reference semantics
        if (dl < TOLF) break;                    // uniform across grid
    }

    // ---- fused epilogue: traj + B output (block b owns batch b; no cross-block dep) ----
    __syncthreads();
    {
        float* Po = (float*)smemB;
        if (t < 512) { if (t < 512) Po[t] = PhiOut[t]; }
    }
    __syncthreads();
    if (t < 256) {
        const float* Po = (const float*)smemB;   // [16][32]
        float cf[32];
        #pragma unroll
        for (int n = 0; n < NTAIL; ++n) cf[2+n] = Bt[((size_t)b*NTAIL + n)*NDIM + t];
        float c0 = yf2i[((size_t)b*2 + 0)*NDIM + t];
        float c1 = yf2i[((size_t)b*2 + 1)*NDIM + t];
        #pragma unroll
        for (int n = 0; n < NTAIL; ++n) { c0 -= cf[2+n]*pd2s[n][0]; c1 -= cf[2+n]*pd2s[n][1]; }
        cf[0] = c0; cf[1] = c1;
        for (int tt = 0; tt < TEV; ++tt) {
            float s = 0.f;
            #pragma unroll
            for (int k = 0; k < 32; ++k) s += cf[k]*Po[tt*32 + k];
            outTraj[((size_t)tt*NBATCH + b)*NDIM + t] = s;
        }
        float* ob = outB + ((size_t)(b*NDIM + t))*NTAIL;
        #pragma unroll
        for (int n = 0; n < NTAIL; ++n) ob[n] = cf[2+n];
    }
}

// ============ fallback dispatch-loop iteration kernel (r2 verbatim) ============
__global__ __launch_bounds__(512, 4) void iter_kernel(
    const float* __restrict__ pd2i, const float* __restrict__ yf2i, const float* __restrict__ tch,
    const bf16_t* __restrict__ W1t, const bf16_t* __restrict__ W2t,
    const float* __restrict__ b1f, const float* __restrict__ b2f,
    const ushort_t* __restrict__ PQhi, const ushort_t* __restrict__ PQlo,
    const ushort_t* __restrict__ phiH, const ushort_t* __restrict__ phiL,
    const float* __restrict__ yM2, float* __restrict__ Bt,
    double* __restrict__ accum, int* __restrict__ counter,
    int* __restrict__ done, float* __restrict__ outDelta)
{
    if (*done) return;
    __shared__ float pd2s[32][2];
    __shared__ float tchS[64];
    __shared__ double redd[8];
    __shared__ __align__(16) char smemA[33792];
    __shared__ __align__(16) char smemB[17408];
    __shared__ __align__(16) ushort_t PQHs[32*72];
    __shared__ __align__(16) ushort_t PQLs[32*72];

    const int t = threadIdx.x;
    const int b = blockIdx.x;
    const int lane = t & 63, w = t >> 6;
    const int fr = lane & 15, quad = lane >> 4;

    if (t < 60) ((float*)pd2s)[t] = pd2i[t];
    if (t >= 64 && t < 128) tchS[t-64] = tch[t-64];
    if (t >= 256) {
        int e = (t - 256) * 8;
        int r = e >> 6, c = e & 63;
        uint4 vh = *(const uint4*)(PQhi + e);
        uint4 vl = *(const uint4*)(PQlo + e);
        *(uint4*)(PQHs + r*72 + c) = vh;
        *(uint4*)(PQLs + r*72 + c) = vl;
    }
    __syncthreads();

    if (t < 256) {
        float cf[32];
        #pragma unroll
        for (int n = 0; n < NTAIL; ++n) cf[2+n] = Bt[((size_t)b*NTAIL + n)*NDIM + t];
        float c0 = yf2i[((size_t)b*2 + 0)*NDIM + t];
        float c1 = yf2i[((size_t)b*2 + 1)*NDIM + t];
        #pragma unroll
        for (int n = 0; n < NTAIL; ++n) { c0 -= cf[2+n]*pd2s[n][0]; c1 -= cf[2+n]*pd2s[n][1]; }
        cf[0] = c0; cf[1] = c1;
        unsigned* BH32 = (unsigned*)smemA;
        unsigned* BL32 = (unsigned*)(smemA + 16384);
        #pragma unroll
        for (int n2 = 0; n2 < 16; ++n2) {
            float f0 = cf[2*n2], f1 = cf[2*n2+1];
            ushort_t h0 = bf16bits(f0), h1 = bf16bits(f1);
            ushort_t l0 = bf16bits(f0 - bf16val(h0)), l1 = bf16bits(f1 - bf16val(h1));
            int idx = t*16 + ((n2 >> 2) ^ (t & 3))*4 + (n2 & 3);
            BH32[idx] = (unsigned)h0 | ((unsigned)h1 << 16);
            BL32[idx] = (unsigned)l0 | ((unsigned)l1 << 16);
        }
    }
    __syncthreads();

    ushort_t* Ay = (ushort_t*)smemA;
    {
        bf16x8 bH[2], bL[2];
        const ushort_t* BHu = (const ushort_t*)smemA;
        const ushort_t* BLu = (const ushort_t*)(smemA + 16384);
        #pragma unroll
        for (int j = 0; j < 2; ++j) {
            const int d = w*32 + j*16 + fr;
            const int off = d*32 + (quad ^ (d & 3))*8;
            bH[j] = *(const bf16x8*)(BHu + off);
            bL[j] = *(const bf16x8*)(BLu + off);
        }
        bf16x8 aH[4], aL[4];
        #pragma unroll
        for (int i = 0; i < 4; ++i) {
            aH[i] = *(const bf16x8*)(phiH + (i*16 + fr)*32 + quad*8);
            aL[i] = *(const bf16x8*)(phiL + (i*16 + fr)*32 + quad*8);
        }
        __syncthreads();
        f32x4 accY[4][2];
        #pragma unroll
        for (int i = 0; i < 4; ++i)
            #pragma unroll
            for (int j = 0; j < 2; ++j) {
                f32x4 a = (f32x4){0.f,0.f,0.f,0.f};
                a = __builtin_amdgcn_mfma_f32_16x16x32_bf16(aH[i], bH[j], a, 0, 0, 0);
                a = __builtin_amdgcn_mfma_f32_16x16x32_bf16(aH[i], bL[j], a, 0, 0, 0);
                a = __builtin_amdgcn_mfma_f32_16x16x32_bf16(aL[i], bH[j], a, 0, 0, 0);
                accY[i][j] = a;
            }
        #pragma unroll
        for (int i = 0; i < 4; ++i)
            #pragma unroll
            for (int j = 0; j < 2; ++j)
                #pragma unroll
                for (int r = 0; r < 4; ++r) {
                    const int p = i*16 + quad*4 + r;
                    const int d = w*32 + j*16 + fr;
                    Ay[p*264 + d] = bf16bits(accY[i][j][r]);
                }
    }
    __syncthreads();

    ushort_t* Hc = (ushort_t*)smemB;
    f32x4 accF[4][2];
    #pragma unroll
    for (int i = 0; i < 4; ++i)
        #pragma unroll
        for (int j = 0; j < 2; ++j) accF[i][j] = (f32x4){0.f,0.f,0.f,0.f};

    #pragma unroll
    for (int pass = 0; pass < 4; ++pass) {
        bf16x8 w2f[4][2];
        #pragma unroll
        for (int kt4 = 0; kt4 < 4; ++kt4)
            #pragma unroll
            for (int j = 0; j < 2; ++j) {
                const int d = w*32 + j*16 + fr;
                w2f[kt4][j] = *(const bf16x8*)(W2t + (size_t)d*NHID + pass*128 + kt4*32 + quad*8);
            }
        f32x4 acc1[4];
        #pragma unroll
        for (int i = 0; i < 4; ++i) acc1[i] = (f32x4){0.f,0.f,0.f,0.f};
        #pragma unroll
        for (int kt = 0; kt < NDIM; kt += 32) {
            bf16x8 af[4], bfv;
            #pragma unroll
            for (int i = 0; i < 4; ++i)
                af[i] = *(const bf16x8*)(Ay + (i*16 + fr)*264 + kt + quad*8);
            {
                const int ncol = pass*128 + w*16 + fr;
                bfv = *(const bf16x8*)(W1t + (size_t)ncol*NDIM + kt + quad*8);
            }
            #pragma unroll
            for (int i = 0; i < 4; ++i)
                acc1[i] = __builtin_amdgcn_mfma_f32_16x16x32_bf16(af[i], bfv, acc1[i], 0, 0, 0);
        }
        __syncthreads();
        {
            const int col = w*16 + fr;
            const float bv = b1f[pass*128 + col];
            #pragma unroll
            for (int i = 0; i < 4; ++i)
                #pragma unroll
                for (int r = 0; r < 4; ++r) {
                    const int row = i*16 + quad*4 + r;
                    float v = acc1[i][r] + bv + tchS[row];
                    v = fminf(fmaxf(v, -15.f), 15.f);
                    float e = __expf(2.f*v);
                    Hc[row*136 + col] = bf16bits((e - 1.f)/(e + 1.f));
                }
        }
        __syncthreads();
        #pragma unroll
        for (int kt4 = 0; kt4 < 4; ++kt4) {
            bf16x8 af[4];
            #pragma unroll
            for (int i = 0; i < 4; ++i)
                af[i] = *(const bf16x8*)(Hc + (i*16 + fr)*136 + kt4*32 + quad*8);
            #pragma unroll
            for (int i = 0; i < 4; ++i)
                #pragma unroll
                for (int j = 0; j < 2; ++j)
                    accF[i][j] = __builtin_amdgcn_mfma_f32_16x16x32_bf16(af[i], w2f[kt4][j], accF[i][j], 0, 0, 0);
        }
    }
    __syncthreads();

    {
        unsigned* FsT32 = (unsigned*)smemA;
        #pragma unroll
        for (int i = 0; i < 4; ++i)
            #pragma unroll
            for (int j = 0; j < 2; ++j) {
                const int d = w*32 + j*16 + fr;
                const float bv = b2f[d];
                #pragma unroll
                for (int rp = 0; rp < 2; ++rp) {
                    unsigned u0 = bf16bits(accF[i][j][rp*2]   + bv);
                    unsigned u1 = bf16bits(accF[i][j][rp*2+1] + bv);
                    FsT32[d*33 + i*8 + quad*2 + rp] = u0 | (u1 << 16);
                }
            }
    }
    __syncthreads();

    double ss = 0.0;
    {
        const ushort_t* FsTu = (const ushort_t*)smemA;
        f32x4 acc2[2][2];
        #pragma unroll
        for (int m2 = 0; m2 < 2; ++m2)
            #pragma unroll
            for (int j2 = 0; j2 < 2; ++j2) acc2[m2][j2] = (f32x4){0.f,0.f,0.f,0.f};
        #pragma unroll
        for (int kk = 0; kk < 2; ++kk) {
            bf16x8 ah[2], al[2];
            #pragma unroll
            for (int m2 = 0; m2 < 2; ++m2) {
                const int off = (m2*16 + fr)*72 + kk*32 + quad*8;
                ah[m2] = *(const bf16x8*)(PQHs + off);
                al[m2] = *(const bf16x8*)(PQLs + off);
            }
            #pragma unroll
            for (int j2 = 0; j2 < 2; ++j2) {
                const int d2 = w*32 + j2*16 + fr;
                bf16x8 bfv = *(const bf16x8*)(FsTu + d2*66 + kk*32 + quad*8);
                #pragma unroll
                for (int m2 = 0; m2 < 2; ++m2) {
                    acc2[m2][j2] = __builtin_amdgcn_mfma_f32_16x16x32_bf16(ah[m2], bfv, acc2[m2][j2], 0, 0, 0);
                    acc2[m2][j2] = __builtin_amdgcn_mfma_f32_16x16x32_bf16(al[m2], bfv, acc2[m2][j2], 0, 0, 0);
                }
            }
        }
        #pragma unroll
        for (int m2 = 0; m2 < 2; ++m2)
            #pragma unroll
            for (int j2 = 0; j2 < 2; ++j2)
                #pragma unroll
                for (int rr = 0; rr < 4; ++rr) {
                    const int n = m2*16 + quad*4 + rr;
                    if (n < NTAIL) {
                        const int d = w*32 + j2*16 + fr;
                        const size_t idx = ((size_t)b*NTAIL + n)*NDIM + d;
                        float val = acc2[m2][j2][rr] - yM2[idx];
                        float old = Bt[idx];
                        float diff = val - old;
                        Bt[idx] = val;
                        ss += (double)diff*(double)diff;
                    }
                }
    }

    #pragma unroll
    for (int off = 32; off > 0; off >>= 1) ss += __shfl_down(ss, off, 64);
    if (lane == 0) redd[w] = ss;
    __syncthreads();
    if (t == 0) {
        double tot = redd[0] + redd[1] + redd[2] + redd[3]
                   + redd[4] + redd[5] + redd[6] + redd[7];
        atomicAdd(accum, tot);
        __threadfence();
        int old = atomicAdd(counter, 1);
        if (old == 511) {
            unsigned long long raw = atomicExch((unsigned long long*)accum, 0ull);
            double total; __builtin_memcpy(&total, &raw, 8);
            float dlv = (float)sqrt(total);
            *outDelta = dlv;
            *counter = 0;
            if (dlv < TOLF) *done = 1;
        }
    }
}

// ============ epilogue (fallback path only) ============
__global__ __launch_bounds__(256) void kernelEpi(const float* __restrict__ PhiOut, const float* __restrict__ pd2i,
                                                 const float* __restrict__ yf2i, const float* __restrict__ Bt,
                                                 float* __restrict__ outTraj, float* __restrict__ outB)
{
    __shared__ float Po[16][32];
    const int t = threadIdx.x, b = blockIdx.x;
    for (int i = t; i < 512; i += 256) ((float*)Po)[i] = PhiOut[i];
    __syncthreads();
    float cf[32];
    #pragma unroll
    for (int n = 0; n < NTAIL; ++n) cf[2+n] = Bt[((size_t)b*NTAIL + n)*NDIM + t];
    float c0 = yf2i[((size_t)b*2 + 0)*NDIM + t];
    float c1 = yf2i[((size_t)b*2 + 1)*NDIM + t];
    #pragma unroll
    for (int n = 0; n < NTAIL; ++n) { c0 -= cf[2+n]*pd2i[n*2]; c1 -= cf[2+n]*pd2i[n*2+1]; }
    cf[0] = c0; cf[1] = c1;
    for (int tt = 0; tt < TEV; ++tt) {
        float s = 0.f;
        #pragma unroll
        for (int k = 0; k < 32; ++k) s += cf[k]*Po[tt][k];
        outTraj[((size_t)tt*NBATCH + b)*NDIM + t] = s;
    }
    float* ob = outB + ((size_t)(b*NDIM + t))*NTAIL;
    #pragma unroll
    for (int n = 0; n < NTAIL; ++n) ob[n] = cf[2+n];
}

extern "C" void kernel_launch(void* const* d_in, const int* in_sizes, int n_in,
                              void* d_out, int out_size, void* d_ws, size_t ws_size,
                              hipStream_t stream)
{
    const float* y_init = (const float*)d_in[0];
    const float* t_eval = (const float*)d_in[1];
    const float* B_init = (const float*)d_in[2];
    const float* W1     = (const float*)d_in[3];
    const float* b1     = (const float*)d_in[4];
    const float* W2     = (const float*)d_in[5];
    const float* b2     = (const float*)d_in[6];
    float* out = (float*)d_out;
    float* ws  = (float*)d_ws;
    if (ws_size < WS_FLOATS * sizeof(float)) return;

    float* tcheb = ws + OFF_TCHEB;
    float* pd2i  = ws + OFF_PD2I;
    float* M2    = ws + OFF_M2;
    float* inv0  = ws + OFF_INV0;
    float* PhiOut= ws + OFF_PHIOUT;
    double* accum = (double*)(ws + OFF_SCAL);
    int* done    = (int*)(ws + OFF_SCAL + 2);
    int* counter = (int*)(ws + OFF_SCAL + 3);
    double* accArr = (double*)(ws + OFF_ACC);
    float* h1   = ws + OFF_H1F;
    float* yf2i = ws + OFF_YF2I;
    float* yM2  = ws + OFF_YM2;
    float* Bt   = ws + OFF_BT;
    bf16_t* W1t = (bf16_t*)(ws + OFF_W1T);
    bf16_t* W2t = (bf16_t*)(ws + OFF_W2T);
    ushort_t* pqh = (ushort_t*)(ws + OFF_PQBH);
    ushort_t* pql = (ushort_t*)(ws + OFF_PQBL);
    ushort_t* phh = (ushort_t*)(ws + OFF_PHIH);
    ushort_t* phl = (ushort_t*)(ws + OFF_PHIL);
    float* outDeltaP = out + OUT_DELTA;
    float* outTrajP  = out + OUT_TRAJ;
    float* outBP     = out + OUT_B;

    setup_kernel<<<1, 256, 0, stream>>>(t_eval, ws, out);
    transB_kernel<<<NBATCH, 256, 0, stream>>>(B_init, Bt);
    transW_kernel<<<dim3(NDIM/64, NHID/64), 256, 0, stream>>>(W1, W1t, NDIM, NHID);
    transW_kernel<<<dim3(NHID/64, NDIM/64), 256, 0, stream>>>(W2, W2t, NHID, NDIM);
    finit_h_kernel<<<NBATCH, 512, 0, stream>>>(y_init, W1, b1, t_eval, h1);
    finit_rest_kernel<<<NBATCH, 256, 0, stream>>>(y_init, W2, b2, h1, inv0, M2, yf2i, yM2);

    const bf16_t* W1tc = W1t; const bf16_t* W2tc = W2t;
    const float* pd2ic = pd2i; const float* yf2ic = yf2i; const float* tchc = tcheb;
    const float* b1c = b1; const float* b2c = b2;
    const ushort_t* pqhc = pqh; const ushort_t* pqlc = pql;
    const ushort_t* phhc = phh; const ushort_t* phlc = phl;
    const float* yM2c = yM2; const float* PhiOutc = PhiOut;

    void* kargs[] = {
        (void*)&pd2ic, (void*)&yf2ic, (void*)&tchc,
        (void*)&W1tc, (void*)&W2tc,
        (void*)&b1c, (void*)&b2c,
        (void*)&pqhc, (void*)&pqlc,
        (void*)&phhc, (void*)&phlc,
        (void*)&yM2c, (void*)&Bt,
        (void*)&accArr, (void*)&outDeltaP,
        (void*)&PhiOutc, (void*)&outTrajP, (void*)&outBP
    };
    hipError_t cerr = hipLaunchCooperativeKernel((const void*)iter_persist,
                                                 dim3(NBATCH), dim3(512),
                                                 kargs, 0, stream);
    if (cerr != hipSuccess) {
        // fallback: proven r2 dispatch loop
        for (int it = 0; it < MAXIT; ++it) {
            iter_kernel<<<NBATCH, 512, 0, stream>>>(pd2i, yf2i, tcheb, W1t, W2t, b1, b2,
                                                    pqh, pql, phh, phl, yM2, Bt,
                                                    accum, counter, done, outDeltaP);
        }
        kernelEpi<<<NBATCH, 256, 0, stream>>>(PhiOut, pd2i, yf2i, Bt, outTrajP, outBP);
    }
}

// Round 6
// 1019.075 us; speedup vs baseline: 2.1019x; 2.1019x over previous
//
#include <hip/hip_runtime.h>
#include <math.h>

#define NBATCH 512
#define NDIM 256
#define NHID 512
#define NC 32
#define NTAIL 30
#define NP 64
#define TEV 16
#define MAXIT 10
#define TOLF 0.01f
#define PI_F 3.14159265358979323846f

typedef __bf16 bf16_t;
typedef __bf16 bf16x8 __attribute__((ext_vector_type(8)));
typedef float f32x4 __attribute__((ext_vector_type(4)));
typedef unsigned short ushort_t;

// ---- workspace layout (float slots) ----
constexpr size_t OFF_TCHEB = 0;        // 64
constexpr size_t OFF_PHIT  = 64;       // 2048
constexpr size_t OFF_PD2I  = 2112;     // 64
constexpr size_t OFF_M2    = 2176;     // 64
constexpr size_t OFF_INV0  = 2240;     // 16
constexpr size_t OFF_PHIOUT= 2256;     // 512
constexpr size_t OFF_PQ    = 2768;     // 2048 (setup scratch)
constexpr size_t OFF_PQBH  = 4816;     // [32][64] bf16 hi (1024 floats)
constexpr size_t OFF_PQBL  = 5840;     // 1024
constexpr size_t OFF_PHIH  = 6864;     // [64][32] bf16 hi of Phi (A-layout), 1024 floats
constexpr size_t OFF_PHIL  = 7888;     // 1024
constexpr size_t OFF_SCAL  = 8912;     // accum double [0:1], done [2], counter [3]
constexpr size_t OFF_H1F   = 8928;
constexpr size_t OFF_YF2I  = OFF_H1F + 262144;
constexpr size_t OFF_YM2   = OFF_YF2I + 262144;
constexpr size_t OFF_BT    = OFF_YM2 + 3932160;
constexpr size_t OFF_W1T   = OFF_BT + 3932160;    // [512][256] bf16
constexpr size_t OFF_W2T   = OFF_W1T + 65536;     // [256][512] bf16
constexpr size_t WS_FLOATS = OFF_W2T + 65536;

// ---- output layout (floats) ----
constexpr size_t OUT_TEVAL = 0;
constexpr size_t OUT_TRAJ  = 16;
constexpr size_t OUT_DELTA = 16 + (size_t)TEV*NBATCH*NDIM;
constexpr size_t OUT_B     = OUT_DELTA + 1;

__device__ __forceinline__ ushort_t bf16bits(float v) {
    bf16_t h = (bf16_t)v; ushort_t u; __builtin_memcpy(&u, &h, 2); return u;
}
__device__ __forceinline__ float bf16val(ushort_t u) {
    bf16_t h; __builtin_memcpy(&h, &u, 2); return (float)h;
}

// ============ setup: spectral operators (round-2/6 proven fp64 parallel GJ) ============
__global__ void setup_kernel(const float* __restrict__ t_eval, float* __restrict__ ws,
                             float* __restrict__ out)
{
    __shared__ float Phi[32][64];
    __shared__ float DPhi[32][64];
    __shared__ float Phib[30][64];
    __shared__ float tcs[64];
    __shared__ float DtS[64];
    __shared__ float inv0s[4];
    __shared__ float pd2s[30][2];
    __shared__ double Gaug[30][61];
    __shared__ double rowk[60];
    __shared__ double colk[30];

    const int tid = threadIdx.x;
    const float t0 = t_eval[0], t1 = t_eval[TEV-1];
    const float sgn = (t1 > t0) ? 1.f : -1.f;

    if (tid < 64) {
        const float t = -sgn * cosf(PI_F * (float)tid / 64.f);
        tcs[tid] = t;
        float p0 = 1.f, p1 = t;
        Phi[0][tid] = p0; Phi[1][tid] = p1;
        for (int k = 2; k < 32; ++k) { float pk = 2.f*t*p1 - p0; Phi[k][tid] = pk; p0 = p1; p1 = pk; }
        const float sc = 2.f / (t1 - t0);
        float u0 = 1.f, u1 = 2.f*t;
        DPhi[0][tid] = 0.f;
        DPhi[1][tid] = sc * 1.f * u0;
        DPhi[2][tid] = sc * 2.f * u1;
        for (int k = 3; k < 32; ++k) { float uk = 2.f*t*u1 - u0; DPhi[k][tid] = sc * (float)k * uk; u0 = u1; u1 = uk; }
    }
    __syncthreads();
    if (tid < 64) DtS[tid] = ((tid < 63) ? tcs[tid+1] : 1.0f) - tcs[tid];
    if (tid == 0) {
        double a = Phi[0][0], b = DPhi[0][0], c = Phi[1][0], d = DPhi[1][0];
        double det = a*d - b*c;
        inv0s[0] = (float)( d/det); inv0s[1] = (float)(-b/det);
        inv0s[2] = (float)(-c/det); inv0s[3] = (float)( a/det);
    }
    __syncthreads();
    if (tid == 0) { ws[OFF_INV0+0]=inv0s[0]; ws[OFF_INV0+1]=inv0s[1]; ws[OFF_INV0+2]=inv0s[2]; ws[OFF_INV0+3]=inv0s[3]; }
    if (tid < 30) {
        float P = Phi[2+tid][0], D = DPhi[2+tid][0];
        float a0 = P*inv0s[0] + D*inv0s[2];
        float a1 = P*inv0s[1] + D*inv0s[3];
        pd2s[tid][0] = a0; pd2s[tid][1] = a1;
        ws[OFF_PD2I + tid*2+0] = a0;
        ws[OFF_PD2I + tid*2+1] = a1;
    }
    __syncthreads();
    if (tid < 64)
        for (int m = 0; m < 30; ++m)
            Phib[m][tid] = DPhi[2+m][tid] - (pd2s[m][0]*DPhi[0][tid] + pd2s[m][1]*DPhi[1][tid]);
    __syncthreads();

    for (int e = tid; e < 900; e += 256) {
        int i = e / 30, j = e % 30;
        double s = 0.0;
        for (int p = 0; p < 64; ++p) s += (double)Phib[i][p] * (double)DtS[p] * (double)Phib[j][p];
        Gaug[i][j] = s;
        Gaug[i][30+j] = (i == j) ? 1.0 : 0.0;
    }
    __syncthreads();

    for (int k = 0; k < 30; ++k) {
        double invpv = 1.0 / Gaug[k][k];
        if (tid < 60) rowk[tid] = Gaug[k][tid] * invpv;
        if (tid >= 64 && tid < 94) colk[tid-64] = Gaug[tid-64][k];
        __syncthreads();
        for (int e = tid; e < 1800; e += 256) {
            int i = e / 60, j = e - i*60;
            if (i == k) Gaug[i][j] = rowk[j];
            else        Gaug[i][j] -= colk[i] * rowk[j];
        }
        __syncthreads();
    }

    if (tid < 64) {
        ushort_t* pqh = (ushort_t*)(ws + OFF_PQBH);
        ushort_t* pql = (ushort_t*)(ws + OFF_PQBL);
        float pqrow[32];
        for (int n = 0; n < 30; ++n) {
            double s = 0.0;
            for (int m = 0; m < 30; ++m) s += (double)Phib[m][tid] * Gaug[m][30+n];
            pqrow[n] = (float)((double)DtS[tid] * s);
        }
        pqrow[30] = 0.f; pqrow[31] = 0.f;
        for (int n = 0; n < 32; ++n) {
            ws[OFF_PQ + (size_t)tid*32 + n] = pqrow[n];
            bf16_t h = (bf16_t)pqrow[n];
            float hf = (float)h;
            pqh[n*64 + tid] = bf16bits(pqrow[n]);
            pql[n*64 + tid] = bf16bits(pqrow[n] - hf);
        }
    }
    __syncthreads();

    if (tid < 30) {
        double a20 = 0.0, a21 = 0.0;
        for (int p = 0; p < 64; ++p) {
            double pq = (double)ws[OFF_PQ + (size_t)p*32 + tid];
            a20 += (double)DPhi[0][p] * pq;
            a21 += (double)DPhi[1][p] * pq;
        }
        ws[OFF_M2 + 0*32 + tid] = (float)((double)inv0s[0]*a20 + (double)inv0s[1]*a21);
        ws[OFF_M2 + 1*32 + tid] = (float)((double)inv0s[2]*a20 + (double)inv0s[3]*a21);
    }

    if (tid < 64) {
        ushort_t* phh = (ushort_t*)(ws + OFF_PHIH);
        ushort_t* phl = (ushort_t*)(ws + OFF_PHIL);
        for (int n = 0; n < 32; ++n) {
            float f = Phi[n][tid];
            ws[OFF_PHIT + (size_t)tid*32 + n] = f;
            ushort_t hb = bf16bits(f);
            phh[tid*32 + n] = hb;
            phl[tid*32 + n] = bf16bits(f - bf16val(hb));
        }
        ws[OFF_TCHEB + tid] = tcs[tid];
    }

    if (tid < TEV) {
        float te = t_eval[tid];
        out[OUT_TEVAL + tid] = te;
        float tt = -1.f + 2.f*(te - t0)/(t1 - t0);
        float q0 = 1.f, q1 = tt;
        ws[OFF_PHIOUT + (size_t)tid*32 + 0] = q0;
        ws[OFF_PHIOUT + (size_t)tid*32 + 1] = q1;
        for (int k = 2; k < 32; ++k) { float qk = 2.f*tt*q1 - q0; ws[OFF_PHIOUT + (size_t)tid*32 + k] = qk; q0 = q1; q1 = qk; }
    }

    if (tid == 0) {
        double* acc = (double*)(ws + OFF_SCAL);
        acc[0] = 0.0;
        int* ip = (int*)(ws + OFF_SCAL + 2);
        ip[0] = 0;  // done
        ip[1] = 0;  // counter
    }
}

// ============ B_init [b][d][n] -> Bt [b][n][d] ============
__global__ __launch_bounds__(256) void transB_kernel(const float* __restrict__ Bin, float* __restrict__ Bt)
{
    const int t = threadIdx.x, b = blockIdx.x;
    const float* src = Bin + ((size_t)(b*NDIM + t)) * NTAIL;
    #pragma unroll
    for (int n = 0; n < NTAIL; ++n)
        Bt[((size_t)b*NTAIL + n)*NDIM + t] = src[n];
}

// ============ W [R][C] f32 -> Wt [C][R] bf16 ============
__global__ __launch_bounds__(256) void transW_kernel(const float* __restrict__ W, bf16_t* __restrict__ Wt,
                                                     int R, int C)
{
    __shared__ float Ls[64][65];
    const int r0 = blockIdx.x*64, c0 = blockIdx.y*64;
    const int lr = threadIdx.x >> 6, lc = threadIdx.x & 63;
    #pragma unroll
    for (int i = 0; i < 16; ++i) {
        int rr = i*4 + lr;
        Ls[rr][lc] = W[(size_t)(r0+rr)*C + c0+lc];
    }
    __syncthreads();
    #pragma unroll
    for (int i = 0; i < 16; ++i) {
        int cc = i*4 + lr;
        Wt[(size_t)(c0+cc)*R + r0 + lc] = (bf16_t)Ls[lc][cc];
    }
}

// ============ f_init ============
__global__ __launch_bounds__(512) void finit_h_kernel(const float* __restrict__ y, const float* __restrict__ W1,
                                                      const float* __restrict__ b1, const float* __restrict__ t_eval,
                                                      float* __restrict__ h1)
{
    __shared__ float ys[NDIM];
    const int t = threadIdx.x, b = blockIdx.x;
    if (t < NDIM) ys[t] = y[(size_t)b*NDIM + t];
    __syncthreads();
    float acc = b1[t] + t_eval[0];
    for (int d = 0; d < NDIM; ++d) acc += ys[d] * W1[(size_t)d*NHID + t];
    h1[(size_t)b*NHID + t] = tanhf(acc);
}

__global__ __launch_bounds__(256) void finit_rest_kernel(const float* __restrict__ y, const float* __restrict__ W2,
                                                         const float* __restrict__ b2, const float* __restrict__ h1,
                                                         const float* __restrict__ inv0, const float* __restrict__ M2,
                                                         float* __restrict__ yf2i, float* __restrict__ yM2)
{
    __shared__ float hs[NHID];
    const int t = threadIdx.x, b = blockIdx.x;
    hs[t] = h1[(size_t)b*NHID + t];
    hs[t+256] = h1[(size_t)b*NHID + 256 + t];
    __syncthreads();
    float f = b2[t];
    for (int h = 0; h < NHID; ++h) f += hs[h] * W2[(size_t)h*NDIM + t];
    const float yv = y[(size_t)b*NDIM + t];
    yf2i[((size_t)b*2 + 0)*NDIM + t] = yv*inv0[0] + f*inv0[2];
    yf2i[((size_t)b*2 + 1)*NDIM + t] = yv*inv0[1] + f*inv0[3];
    #pragma unroll
    for (int n = 0; n < NTAIL; ++n)
        yM2[((size_t)b*NTAIL + n)*NDIM + t] = yv*M2[n] + f*M2[32 + n];
}

// ============ fused iteration kernel ============
// Round-12: r2's body math at 1024 threads (16 waves), 512 blocks, 2 blocks/CU
// -> 32 waves/CU (hardware max, 8/SIMD — double r2's 4/SIMD).
// Each wave owns 16 d-cols (j-loop gone); NH pass loop 4 -> 2 (Hc widens to
// [64][264], LDS ~77.5 KB, 2 blocks/CU = 155/160 KB). Barrier phases 13 -> ~9;
// per-wave LDS b128 reads halve; per-thread tanh VALU halves. Block-total LDS
// traffic unchanged — if this lands >=58 µs/iter, LDS pipe is the ceiling.
// NOTE (r5 post-mortem): cooperative grid.sync() forces cross-XCD L2
// writeback/invalidate on gfx950 -> 9x HBM traffic. Never persist this kernel.
__global__ __launch_bounds__(1024, 8) void iter_kernel(
    const float* __restrict__ pd2i, const float* __restrict__ yf2i, const float* __restrict__ tch,
    const bf16_t* __restrict__ W1t, const bf16_t* __restrict__ W2t,
    const float* __restrict__ b1f, const float* __restrict__ b2f,
    const ushort_t* __restrict__ PQhi, const ushort_t* __restrict__ PQlo,
    const ushort_t* __restrict__ phiH, const ushort_t* __restrict__ phiL,
    const float* __restrict__ yM2, float* __restrict__ Bt,
    double* __restrict__ accum, int* __restrict__ counter,
    int* __restrict__ done, float* __restrict__ outDelta)
{
    if (*done) return;
    __shared__ float pd2s[32][2];
    __shared__ float tchS[64];
    __shared__ double redd[16];
    __shared__ __align__(16) char smemA[33792];  // BfT hi/lo -> Ay [64][264]us -> FsT [256][33]u32
    __shared__ __align__(16) char smemB[33792];  // Hc [64][264]us
    __shared__ __align__(16) ushort_t PQHs[32*72];
    __shared__ __align__(16) ushort_t PQLs[32*72];

    const int t = threadIdx.x;
    const int b = blockIdx.x;            // batch index 0..511
    const int lane = t & 63, w = t >> 6;             // w 0..15
    const int fr = lane & 15, quad = lane >> 4;
    const int dcol = w*16 + fr;                      // this thread's d-column (0..255)

    // ---- constants into LDS: waves 0-1 do pd2s/tch, waves 4-7 stage PQ ----
    if (t < 60) ((float*)pd2s)[t] = pd2i[t];
    if (t >= 64 && t < 128) tchS[t-64] = tch[t-64];
    if (t >= 256 && t < 512) {
        int e = (t - 256) * 8;           // 256 threads x 8 ushorts = 2048
        int r = e >> 6, c = e & 63;
        uint4 vh = *(const uint4*)(PQhi + e);
        uint4 vl = *(const uint4*)(PQlo + e);
        *(uint4*)(PQHs + r*72 + c) = vh;
        *(uint4*)(PQLs + r*72 + c) = vl;
    }
    __syncthreads();   // pd2s visible to all threads

    // ---- stage 0a: head coefficients (threads 0..255, t = d), write BfT hi/lo swizzled ----
    if (t < 256) {
        float cf[32];
        #pragma unroll
        for (int n = 0; n < NTAIL; ++n) cf[2+n] = Bt[((size_t)b*NTAIL + n)*NDIM + t];
        float c0 = yf2i[((size_t)b*2 + 0)*NDIM + t];
        float c1 = yf2i[((size_t)b*2 + 1)*NDIM + t];
        #pragma unroll
        for (int n = 0; n < NTAIL; ++n) { c0 -= cf[2+n]*pd2s[n][0]; c1 -= cf[2+n]*pd2s[n][1]; }
        cf[0] = c0; cf[1] = c1;
        unsigned* BH32 = (unsigned*)smemA;             // [256][16] u32 (block-swizzled)
        unsigned* BL32 = (unsigned*)(smemA + 16384);
        #pragma unroll
        for (int n2 = 0; n2 < 16; ++n2) {
            float f0 = cf[2*n2], f1 = cf[2*n2+1];
            ushort_t h0 = bf16bits(f0), h1 = bf16bits(f1);
            ushort_t l0 = bf16bits(f0 - bf16val(h0)), l1 = bf16bits(f1 - bf16val(h1));
            int idx = t*16 + ((n2 >> 2) ^ (t & 3))*4 + (n2 & 3);
            BH32[idx] = (unsigned)h0 | ((unsigned)h1 << 16);
            BL32[idx] = (unsigned)l0 | ((unsigned)l1 << 16);
        }
    }
    __syncthreads();

    // ---- stage 0b: y = Phi @ Bfull via MFMA (hi/lo 3-product), write Ay [64 p][264] bf16 ----
    ushort_t* Ay = (ushort_t*)smemA;
    {
        bf16x8 bH, bL;
        const ushort_t* BHu = (const ushort_t*)smemA;
        const ushort_t* BLu = (const ushort_t*)(smemA + 16384);
        {
            const int off = dcol*32 + (quad ^ (dcol & 3))*8;
            bH = *(const bf16x8*)(BHu + off);
            bL = *(const bf16x8*)(BLu + off);
        }
        bf16x8 aH[4], aL[4];
        #pragma unroll
        for (int i = 0; i < 4; ++i) {
            aH[i] = *(const bf16x8*)(phiH + (i*16 + fr)*32 + quad*8);
            aL[i] = *(const bf16x8*)(phiL + (i*16 + fr)*32 + quad*8);
        }
        __syncthreads();   // all BfT reads done before Ay overwrite
        f32x4 accY[4];
        #pragma unroll
        for (int i = 0; i < 4; ++i) {
            f32x4 a = (f32x4){0.f,0.f,0.f,0.f};
            a = __builtin_amdgcn_mfma_f32_16x16x32_bf16(aH[i], bH, a, 0, 0, 0);
            a = __builtin_amdgcn_mfma_f32_16x16x32_bf16(aH[i], bL, a, 0, 0, 0);
            a = __builtin_amdgcn_mfma_f32_16x16x32_bf16(aL[i], bH, a, 0, 0, 0);
            accY[i] = a;
        }
        #pragma unroll
        for (int i = 0; i < 4; ++i)
            #pragma unroll
            for (int r = 0; r < 4; ++r) {
                const int p = i*16 + quad*4 + r;
                Ay[p*264 + dcol] = bf16bits(accY[i][r]);
            }
    }
    __syncthreads();

    // ---- GEMM1 + tanh + GEMM2 over 2 nh-passes of 256; W2 frags register-prefetched per pass ----
    ushort_t* Hc = (ushort_t*)smemB;     // [64][264]
    f32x4 accF[4];                       // rows i*16, d-col dcol
    #pragma unroll
    for (int i = 0; i < 4; ++i) accF[i] = (f32x4){0.f,0.f,0.f,0.f};

    #pragma unroll
    for (int pass = 0; pass < 2; ++pass) {
        // prefetch ALL W2 fragments for this pass; they land during GEMM1's MFMA burst
        bf16x8 w2f[8];   // [kt/32]
        #pragma unroll
        for (int kt4 = 0; kt4 < 8; ++kt4)
            w2f[kt4] = *(const bf16x8*)(W2t + (size_t)dcol*NHID + pass*256 + kt4*32 + quad*8);
        // GEMM1: acc1 = y(64x256) @ W1 chunk (256 x 256); each wave owns 16 h-cols
        f32x4 acc1[4];
        #pragma unroll
        for (int i = 0; i < 4; ++i) acc1[i] = (f32x4){0.f,0.f,0.f,0.f};
        #pragma unroll
        for (int kt = 0; kt < NDIM; kt += 32) {
            bf16x8 af[4], bfv;
            #pragma unroll
            for (int i = 0; i < 4; ++i)
                af[i] = *(const bf16x8*)(Ay + (i*16 + fr)*264 + kt + quad*8);
            {
                const int ncol = pass*256 + w*16 + fr;
                bfv = *(const bf16x8*)(W1t + (size_t)ncol*NDIM + kt + quad*8);
            }
            #pragma unroll
            for (int i = 0; i < 4; ++i)
                acc1[i] = __builtin_amdgcn_mfma_f32_16x16x32_bf16(af[i], bfv, acc1[i], 0, 0, 0);
        }
        __syncthreads();   // prev pass GEMM2 Hc reads done (also drains w2f loads)
        {
            const int col = w*16 + fr;
            const float bv = b1f[pass*256 + col];
            #pragma unroll
            for (int i = 0; i < 4; ++i)
                #pragma unroll
                for (int r = 0; r < 4; ++r) {
                    const int row = i*16 + quad*4 + r;   // = p, 0..63
                    float v = acc1[i][r] + bv + tchS[row];
                    v = fminf(fmaxf(v, -15.f), 15.f);
                    float e = __expf(2.f*v);
                    Hc[row*264 + col] = bf16bits((e - 1.f)/(e + 1.f));
                }
        }
        __syncthreads();
        // GEMM2 partial: accF += Hc(64x256) @ W2 chunk (256 x 256) — no global loads here
        #pragma unroll
        for (int kt4 = 0; kt4 < 8; ++kt4) {
            bf16x8 af[4];
            #pragma unroll
            for (int i = 0; i < 4; ++i)
                af[i] = *(const bf16x8*)(Hc + (i*16 + fr)*264 + kt4*32 + quad*8);
            #pragma unroll
            for (int i = 0; i < 4; ++i)
                accF[i] = __builtin_amdgcn_mfma_f32_16x16x32_bf16(af[i], w2f[kt4], accF[i], 0, 0, 0);
        }
    }
    __syncthreads();   // last GEMM1's Ay reads done; smemA reusable

    // ---- F (+b2) -> FsT [256 d][33] u32 (bf16 row-pairs) ----
    {
        unsigned* FsT32 = (unsigned*)smemA;
        const float bv = b2f[dcol];
        #pragma unroll
        for (int i = 0; i < 4; ++i)
            #pragma unroll
            for (int rp = 0; rp < 2; ++rp) {
                unsigned u0 = bf16bits(accF[i][rp*2]   + bv);
                unsigned u1 = bf16bits(accF[i][rp*2+1] + bv);
                FsT32[dcol*33 + i*8 + quad*2 + rp] = u0 | (u1 << 16);
            }
    }
    __syncthreads();

    // ---- PQ contraction: B_new[n][d] = sum_p PQ[n][p]*F[p][d] - yM2, update Bt + norm ----
    double ss = 0.0;
    {
        const ushort_t* FsTu = (const ushort_t*)smemA;
        f32x4 acc2[2];
        #pragma unroll
        for (int m2 = 0; m2 < 2; ++m2) acc2[m2] = (f32x4){0.f,0.f,0.f,0.f};
        #pragma unroll
        for (int kk = 0; kk < 2; ++kk) {
            bf16x8 ah[2], al[2];
            #pragma unroll
            for (int m2 = 0; m2 < 2; ++m2) {
                const int off = (m2*16 + fr)*72 + kk*32 + quad*8;
                ah[m2] = *(const bf16x8*)(PQHs + off);
                al[m2] = *(const bf16x8*)(PQLs + off);
            }
            bf16x8 bfv = *(const bf16x8*)(FsTu + dcol*66 + kk*32 + quad*8);
            #pragma unroll
            for (int m2 = 0; m2 < 2; ++m2) {
                acc2[m2] = __builtin_amdgcn_mfma_f32_16x16x32_bf16(ah[m2], bfv, acc2[m2], 0, 0, 0);
                acc2[m2] = __builtin_amdgcn_mfma_f32_16x16x32_bf16(al[m2], bfv, acc2[m2], 0, 0, 0);
            }
        }
        #pragma unroll
        for (int m2 = 0; m2 < 2; ++m2)
            #pragma unroll
            for (int rr = 0; rr < 4; ++rr) {
                const int n = m2*16 + quad*4 + rr;
                if (n < NTAIL) {
                    const size_t idx = ((size_t)b*NTAIL + n)*NDIM + dcol;
                    float val = acc2[m2][rr] - yM2[idx];
                    float old = Bt[idx];
                    float diff = val - old;
                    Bt[idx] = val;
                    ss += (double)diff*(double)diff;
                }
            }
    }

    #pragma unroll
    for (int off = 32; off > 0; off >>= 1) ss += __shfl_down(ss, off, 64);
    if (lane == 0) redd[w] = ss;
    __syncthreads();
    if (t == 0) {
        double tot = 0.0;
        #pragma unroll
        for (int i = 0; i < 16; ++i) tot += redd[i];
        atomicAdd(accum, tot);
        __threadfence();
        int old = atomicAdd(counter, 1);
        if (old == 511) {   // last of 512 blocks
            unsigned long long raw = atomicExch((unsigned long long*)accum, 0ull);
            double total; __builtin_memcpy(&total, &raw, 8);
            float dl = (float)sqrt(total);
            *outDelta = dl;
            *counter = 0;
            if (dl < TOLF) *done = 1;
        }
    }
}

// ============ epilogue: traj + B output ============
__global__ __launch_bounds__(256) void kernelEpi(const float* __restrict__ PhiOut, const float* __restrict__ pd2i,
                                                 const float* __restrict__ yf2i, const float* __restrict__ Bt,
                                                 float* __restrict__ outTraj, float* __restrict__ outB)
{
    __shared__ float Po[16][32];
    const int t = threadIdx.x, b = blockIdx.x;
    for (int i = t; i < 512; i += 256) ((float*)Po)[i] = PhiOut[i];
    __syncthreads();
    float cf[32];
    #pragma unroll
    for (int n = 0; n < NTAIL; ++n) cf[2+n] = Bt[((size_t)b*NTAIL + n)*NDIM + t];
    float c0 = yf2i[((size_t)b*2 + 0)*NDIM + t];
    float c1 = yf2i[((size_t)b*2 + 1)*NDIM + t];
    #pragma unroll
    for (int n = 0; n < NTAIL; ++n) { c0 -= cf[2+n]*pd2i[n*2]; c1 -= cf[2+n]*pd2i[n*2+1]; }
    cf[0] = c0; cf[1] = c1;
    for (int tt = 0; tt < TEV; ++tt) {
        float s = 0.f;
        #pragma unroll
        for (int k = 0; k < 32; ++k) s += cf[k]*Po[tt][k];
        outTraj[((size_t)tt*NBATCH + b)*NDIM + t] = s;
    }
    float* ob = outB + ((size_t)(b*NDIM + t))*NTAIL;
    #pragma unroll
    for (int n = 0; n < NTAIL; ++n) ob[n] = cf[2+n];
}

extern "C" void kernel_launch(void* const* d_in, const int* in_sizes, int n_in,
                              void* d_out, int out_size, void* d_ws, size_t ws_size,
                              hipStream_t stream)
{
    const float* y_init = (const float*)d_in[0];
    const float* t_eval = (const float*)d_in[1];
    const float* B_init = (const float*)d_in[2];
    const float* W1     = (const float*)d_in[3];
    const float* b1     = (const float*)d_in[4];
    const float* W2     = (const float*)d_in[5];
    const float* b2     = (const float*)d_in[6];
    float* out = (float*)d_out;
    float* ws  = (float*)d_ws;
    if (ws_size < WS_FLOATS * sizeof(float)) return;

    float* tcheb = ws + OFF_TCHEB;
    float* pd2i  = ws + OFF_PD2I;
    float* M2    = ws + OFF_M2;
    float* inv0  = ws + OFF_INV0;
    float* PhiOut= ws + OFF_PHIOUT;
    double* accum = (double*)(ws + OFF_SCAL);
    int* done    = (int*)(ws + OFF_SCAL + 2);
    int* counter = (int*)(ws + OFF_SCAL + 3);
    float* h1   = ws + OFF_H1F;
    float* yf2i = ws + OFF_YF2I;
    float* yM2  = ws + OFF_YM2;
    float* Bt   = ws + OFF_BT;
    bf16_t* W1t = (bf16_t*)(ws + OFF_W1T);
    bf16_t* W2t = (bf16_t*)(ws + OFF_W2T);
    ushort_t* pqh = (ushort_t*)(ws + OFF_PQBH);
    ushort_t* pql = (ushort_t*)(ws + OFF_PQBL);
    ushort_t* phh = (ushort_t*)(ws + OFF_PHIH);
    ushort_t* phl = (ushort_t*)(ws + OFF_PHIL);

    setup_kernel<<<1, 256, 0, stream>>>(t_eval, ws, out);
    transB_kernel<<<NBATCH, 256, 0, stream>>>(B_init, Bt);
    transW_kernel<<<dim3(NDIM/64, NHID/64), 256, 0, stream>>>(W1, W1t, NDIM, NHID);
    transW_kernel<<<dim3(NHID/64, NDIM/64), 256, 0, stream>>>(W2, W2t, NHID, NDIM);
    finit_h_kernel<<<NBATCH, 512, 0, stream>>>(y_init, W1, b1, t_eval, h1);
    finit_rest_kernel<<<NBATCH, 256, 0, stream>>>(y_init, W2, b2, h1, inv0, M2, yf2i, yM2);

    for (int it = 0; it < MAXIT; ++it) {
        iter_kernel<<<NBATCH, 1024, 0, stream>>>(pd2i, yf2i, tcheb, W1t, W2t, b1, b2,
                                                 pqh, pql, phh, phl, yM2, Bt,
                                                 accum, counter, done, out + OUT_DELTA);
    }
    kernelEpi<<<NBATCH, 256, 0, stream>>>(PhiOut, pd2i, yf2i, Bt, out + OUT_TRAJ, out + OUT_B);
}

// Round 7
// 705.200 us; speedup vs baseline: 3.0374x; 1.4451x over previous
//
#include <hip/hip_runtime.h>
#include <math.h>

#define NBATCH 512
#define NDIM 256
#define NHID 512
#define NC 32
#define NTAIL 30
#define NP 64
#define TEV 16
#define MAXIT 10
#define TOLF 0.01f
#define PI_F 3.14159265358979323846f

typedef __bf16 bf16_t;
typedef __bf16 bf16x8 __attribute__((ext_vector_type(8)));
typedef float f32x4 __attribute__((ext_vector_type(4)));
typedef unsigned short ushort_t;

// ---- workspace layout (float slots) ----
constexpr size_t OFF_TCHEB = 0;        // 64
constexpr size_t OFF_PHIT  = 64;       // 2048
constexpr size_t OFF_PD2I  = 2112;     // 64
constexpr size_t OFF_M2    = 2176;     // 64
constexpr size_t OFF_INV0  = 2240;     // 16
constexpr size_t OFF_PHIOUT= 2256;     // 512
constexpr size_t OFF_PQ    = 2768;     // 2048 (setup scratch)
constexpr size_t OFF_PQBH  = 4816;     // [32][64] bf16 hi (1024 floats)
constexpr size_t OFF_PQBL  = 5840;     // 1024
constexpr size_t OFF_PHIH  = 6864;     // [64][32] bf16 hi of Phi (A-layout), 1024 floats
constexpr size_t OFF_PHIL  = 7888;     // 1024
constexpr size_t OFF_SCAL  = 8912;     // accum double [0:1], done [2], counter [3]
constexpr size_t OFF_H1F   = 8928;
constexpr size_t OFF_YF2I  = OFF_H1F + 262144;
constexpr size_t OFF_YFR   = OFF_YF2I + 262144;   // [512][2][256] raw yv,f (rank-2 yM2 replacement)
constexpr size_t OFF_BT    = OFF_YFR + 3932160;   // (region kept; only 262144 used at OFF_YFR)
constexpr size_t OFF_W1T   = OFF_BT + 3932160;    // [512][256] bf16
constexpr size_t OFF_W2T   = OFF_W1T + 65536;     // [256][512] bf16
constexpr size_t WS_FLOATS = OFF_W2T + 65536;

// ---- output layout (floats) ----
constexpr size_t OUT_TEVAL = 0;
constexpr size_t OUT_TRAJ  = 16;
constexpr size_t OUT_DELTA = 16 + (size_t)TEV*NBATCH*NDIM;
constexpr size_t OUT_B     = OUT_DELTA + 1;

__device__ __forceinline__ ushort_t bf16bits(float v) {
    bf16_t h = (bf16_t)v; ushort_t u; __builtin_memcpy(&u, &h, 2); return u;
}
__device__ __forceinline__ float bf16val(ushort_t u) {
    bf16_t h; __builtin_memcpy(&h, &u, 2); return (float)h;
}

// ============ setup: spectral operators (round-2/6 proven fp64 parallel GJ) ============
__global__ void setup_kernel(const float* __restrict__ t_eval, float* __restrict__ ws,
                             float* __restrict__ out)
{
    __shared__ float Phi[32][64];
    __shared__ float DPhi[32][64];
    __shared__ float Phib[30][64];
    __shared__ float tcs[64];
    __shared__ float DtS[64];
    __shared__ float inv0s[4];
    __shared__ float pd2s[30][2];
    __shared__ double Gaug[30][61];
    __shared__ double rowk[60];
    __shared__ double colk[30];

    const int tid = threadIdx.x;
    const float t0 = t_eval[0], t1 = t_eval[TEV-1];
    const float sgn = (t1 > t0) ? 1.f : -1.f;

    if (tid < 64) {
        const float t = -sgn * cosf(PI_F * (float)tid / 64.f);
        tcs[tid] = t;
        float p0 = 1.f, p1 = t;
        Phi[0][tid] = p0; Phi[1][tid] = p1;
        for (int k = 2; k < 32; ++k) { float pk = 2.f*t*p1 - p0; Phi[k][tid] = pk; p0 = p1; p1 = pk; }
        const float sc = 2.f / (t1 - t0);
        float u0 = 1.f, u1 = 2.f*t;
        DPhi[0][tid] = 0.f;
        DPhi[1][tid] = sc * 1.f * u0;
        DPhi[2][tid] = sc * 2.f * u1;
        for (int k = 3; k < 32; ++k) { float uk = 2.f*t*u1 - u0; DPhi[k][tid] = sc * (float)k * uk; u0 = u1; u1 = uk; }
    }
    __syncthreads();
    if (tid < 64) DtS[tid] = ((tid < 63) ? tcs[tid+1] : 1.0f) - tcs[tid];
    if (tid == 0) {
        double a = Phi[0][0], b = DPhi[0][0], c = Phi[1][0], d = DPhi[1][0];
        double det = a*d - b*c;
        inv0s[0] = (float)( d/det); inv0s[1] = (float)(-b/det);
        inv0s[2] = (float)(-c/det); inv0s[3] = (float)( a/det);
    }
    __syncthreads();
    if (tid == 0) { ws[OFF_INV0+0]=inv0s[0]; ws[OFF_INV0+1]=inv0s[1]; ws[OFF_INV0+2]=inv0s[2]; ws[OFF_INV0+3]=inv0s[3]; }
    if (tid < 30) {
        float P = Phi[2+tid][0], D = DPhi[2+tid][0];
        float a0 = P*inv0s[0] + D*inv0s[2];
        float a1 = P*inv0s[1] + D*inv0s[3];
        pd2s[tid][0] = a0; pd2s[tid][1] = a1;
        ws[OFF_PD2I + tid*2+0] = a0;
        ws[OFF_PD2I + tid*2+1] = a1;
    }
    __syncthreads();
    if (tid < 64)
        for (int m = 0; m < 30; ++m)
            Phib[m][tid] = DPhi[2+m][tid] - (pd2s[m][0]*DPhi[0][tid] + pd2s[m][1]*DPhi[1][tid]);
    __syncthreads();

    for (int e = tid; e < 900; e += 256) {
        int i = e / 30, j = e % 30;
        double s = 0.0;
        for (int p = 0; p < 64; ++p) s += (double)Phib[i][p] * (double)DtS[p] * (double)Phib[j][p];
        Gaug[i][j] = s;
        Gaug[i][30+j] = (i == j) ? 1.0 : 0.0;
    }
    __syncthreads();

    for (int k = 0; k < 30; ++k) {
        double invpv = 1.0 / Gaug[k][k];
        if (tid < 60) rowk[tid] = Gaug[k][tid] * invpv;
        if (tid >= 64 && tid < 94) colk[tid-64] = Gaug[tid-64][k];
        __syncthreads();
        for (int e = tid; e < 1800; e += 256) {
            int i = e / 60, j = e - i*60;
            if (i == k) Gaug[i][j] = rowk[j];
            else        Gaug[i][j] -= colk[i] * rowk[j];
        }
        __syncthreads();
    }

    if (tid < 64) {
        ushort_t* pqh = (ushort_t*)(ws + OFF_PQBH);
        ushort_t* pql = (ushort_t*)(ws + OFF_PQBL);
        float pqrow[32];
        for (int n = 0; n < 30; ++n) {
            double s = 0.0;
            for (int m = 0; m < 30; ++m) s += (double)Phib[m][tid] * Gaug[m][30+n];
            pqrow[n] = (float)((double)DtS[tid] * s);
        }
        pqrow[30] = 0.f; pqrow[31] = 0.f;
        for (int n = 0; n < 32; ++n) {
            ws[OFF_PQ + (size_t)tid*32 + n] = pqrow[n];
            bf16_t h = (bf16_t)pqrow[n];
            float hf = (float)h;
            pqh[n*64 + tid] = bf16bits(pqrow[n]);
            pql[n*64 + tid] = bf16bits(pqrow[n] - hf);
        }
    }
    __syncthreads();

    if (tid < 30) {
        double a20 = 0.0, a21 = 0.0;
        for (int p = 0; p < 64; ++p) {
            double pq = (double)ws[OFF_PQ + (size_t)p*32 + tid];
            a20 += (double)DPhi[0][p] * pq;
            a21 += (double)DPhi[1][p] * pq;
        }
        ws[OFF_M2 + 0*32 + tid] = (float)((double)inv0s[0]*a20 + (double)inv0s[1]*a21);
        ws[OFF_M2 + 1*32 + tid] = (float)((double)inv0s[2]*a20 + (double)inv0s[3]*a21);
    }

    if (tid < 64) {
        ushort_t* phh = (ushort_t*)(ws + OFF_PHIH);
        ushort_t* phl = (ushort_t*)(ws + OFF_PHIL);
        for (int n = 0; n < 32; ++n) {
            float f = Phi[n][tid];
            ws[OFF_PHIT + (size_t)tid*32 + n] = f;
            ushort_t hb = bf16bits(f);
            phh[tid*32 + n] = hb;
            phl[tid*32 + n] = bf16bits(f - bf16val(hb));
        }
        ws[OFF_TCHEB + tid] = tcs[tid];
    }

    if (tid < TEV) {
        float te = t_eval[tid];
        out[OUT_TEVAL + tid] = te;
        float tt = -1.f + 2.f*(te - t0)/(t1 - t0);
        float q0 = 1.f, q1 = tt;
        ws[OFF_PHIOUT + (size_t)tid*32 + 0] = q0;
        ws[OFF_PHIOUT + (size_t)tid*32 + 1] = q1;
        for (int k = 2; k < 32; ++k) { float qk = 2.f*tt*q1 - q0; ws[OFF_PHIOUT + (size_t)tid*32 + k] = qk; q0 = q1; q1 = qk; }
    }

    if (tid == 0) {
        double* acc = (double*)(ws + OFF_SCAL);
        acc[0] = 0.0;
        int* ip = (int*)(ws + OFF_SCAL + 2);
        ip[0] = 0;  // done
        ip[1] = 0;  // counter
    }
}

// ============ B_init [b][d][n] -> Bt [b][n][d] ============
__global__ __launch_bounds__(256) void transB_kernel(const float* __restrict__ Bin, float* __restrict__ Bt)
{
    const int t = threadIdx.x, b = blockIdx.x;
    const float* src = Bin + ((size_t)(b*NDIM + t)) * NTAIL;
    #pragma unroll
    for (int n = 0; n < NTAIL; ++n)
        Bt[((size_t)b*NTAIL + n)*NDIM + t] = src[n];
}

// ============ W [R][C] f32 -> Wt [C][R] bf16 ============
__global__ __launch_bounds__(256) void transW_kernel(const float* __restrict__ W, bf16_t* __restrict__ Wt,
                                                     int R, int C)
{
    __shared__ float Ls[64][65];
    const int r0 = blockIdx.x*64, c0 = blockIdx.y*64;
    const int lr = threadIdx.x >> 6, lc = threadIdx.x & 63;
    #pragma unroll
    for (int i = 0; i < 16; ++i) {
        int rr = i*4 + lr;
        Ls[rr][lc] = W[(size_t)(r0+rr)*C + c0+lc];
    }
    __syncthreads();
    #pragma unroll
    for (int i = 0; i < 16; ++i) {
        int cc = i*4 + lr;
        Wt[(size_t)(c0+cc)*R + r0 + lc] = (bf16_t)Ls[lc][cc];
    }
}

// ============ f_init ============
__global__ __launch_bounds__(512) void finit_h_kernel(const float* __restrict__ y, const float* __restrict__ W1,
                                                      const float* __restrict__ b1, const float* __restrict__ t_eval,
                                                      float* __restrict__ h1)
{
    __shared__ float ys[NDIM];
    const int t = threadIdx.x, b = blockIdx.x;
    if (t < NDIM) ys[t] = y[(size_t)b*NDIM + t];
    __syncthreads();
    float acc = b1[t] + t_eval[0];
    for (int d = 0; d < NDIM; ++d) acc += ys[d] * W1[(size_t)d*NHID + t];
    h1[(size_t)b*NHID + t] = tanhf(acc);
}

// Round-13: writes raw (yv, f) instead of the materialized 15.7 MB yM2 tensor.
// yM2[b,n,d] = yv[b,d]*M2[n] + f[b,d]*M2[32+n] is rank-2 in n — reconstructed
// on the fly in iter_kernel (bit-identical f32 math, 2 FMAs per output).
__global__ __launch_bounds__(256) void finit_rest_kernel(const float* __restrict__ y, const float* __restrict__ W2,
                                                         const float* __restrict__ b2, const float* __restrict__ h1,
                                                         const float* __restrict__ inv0,
                                                         float* __restrict__ yf2i, float* __restrict__ yfr)
{
    __shared__ float hs[NHID];
    const int t = threadIdx.x, b = blockIdx.x;
    hs[t] = h1[(size_t)b*NHID + t];
    hs[t+256] = h1[(size_t)b*NHID + 256 + t];
    __syncthreads();
    float f = b2[t];
    for (int h = 0; h < NHID; ++h) f += hs[h] * W2[(size_t)h*NDIM + t];
    const float yv = y[(size_t)b*NDIM + t];
    yf2i[((size_t)b*2 + 0)*NDIM + t] = yv*inv0[0] + f*inv0[2];
    yf2i[((size_t)b*2 + 1)*NDIM + t] = yv*inv0[1] + f*inv0[3];
    yfr[((size_t)b*2 + 0)*NDIM + t] = yv;
    yfr[((size_t)b*2 + 1)*NDIM + t] = f;
}

// ============ fused iteration kernel ============
// 512 blocks x 512 threads (8 waves), 2 blocks/CU -> 16 waves/CU. r2 body.
// Round-13 changes:
//  (a) yM2 stream (15.7 MB f32 HBM read per iteration — ~80% of FETCH_SIZE)
//      replaced by rank-2 on-the-fly reconstruction from yfr (1 MB, L2-hot):
//      val = acc2 - (yv[d]*M2[n] + f[d]*M2[32+n]).  Also shrinks the per-XCD
//      L2 working set ~4.2 -> ~2.5 MB so Bt/weights stay resident.
//  (b) PQ->LDS staging moved into stage-0a's else-branch: waves 4-7 (idle
//      there in r2) now stage PQ concurrently with waves 0-3's 0a work.
// NOTE (r5): never make this cooperative/persistent — grid.sync() on gfx950
// forces cross-XCD L2 writeback (9x HBM). NOTE (r6): 1024 threads spills
// (VGPR cap 64 at 8 waves/SIMD).
__global__ __launch_bounds__(512, 4) void iter_kernel(
    const float* __restrict__ pd2i, const float* __restrict__ yf2i, const float* __restrict__ tch,
    const bf16_t* __restrict__ W1t, const bf16_t* __restrict__ W2t,
    const float* __restrict__ b1f, const float* __restrict__ b2f,
    const ushort_t* __restrict__ PQhi, const ushort_t* __restrict__ PQlo,
    const ushort_t* __restrict__ phiH, const ushort_t* __restrict__ phiL,
    const float* __restrict__ yfr, const float* __restrict__ M2f,
    float* __restrict__ Bt,
    double* __restrict__ accum, int* __restrict__ counter,
    int* __restrict__ done, float* __restrict__ outDelta)
{
    if (*done) return;
    __shared__ float pd2s[32][2];
    __shared__ float tchS[64];
    __shared__ float m2S[64];
    __shared__ double redd[8];
    __shared__ __align__(16) char smemA[33792];  // BfT hi/lo -> Ay [64][264]us -> FsT [256][33]u32
    __shared__ __align__(16) char smemB[17408];  // Hc [64][136]us
    __shared__ __align__(16) ushort_t PQHs[32*72];
    __shared__ __align__(16) ushort_t PQLs[32*72];

    const int t = threadIdx.x;
    const int b = blockIdx.x;            // batch index 0..511
    const int lane = t & 63, w = t >> 6;             // w 0..7
    const int fr = lane & 15, quad = lane >> 4;

    // ---- tiny constants into LDS (pd2s needed immediately by 0a) ----
    if (t < 60) ((float*)pd2s)[t] = pd2i[t];
    if (t >= 64 && t < 128) tchS[t-64] = tch[t-64];
    if (t >= 128 && t < 192) m2S[t-128] = M2f[t-128];
    __syncthreads();

    // ---- stage 0a (threads 0..255) CONCURRENT with PQ staging (threads 256..511) ----
    if (t < 256) {
        float cf[32];
        #pragma unroll
        for (int n = 0; n < NTAIL; ++n) cf[2+n] = Bt[((size_t)b*NTAIL + n)*NDIM + t];
        float c0 = yf2i[((size_t)b*2 + 0)*NDIM + t];
        float c1 = yf2i[((size_t)b*2 + 1)*NDIM + t];
        #pragma unroll
        for (int n = 0; n < NTAIL; ++n) { c0 -= cf[2+n]*pd2s[n][0]; c1 -= cf[2+n]*pd2s[n][1]; }
        cf[0] = c0; cf[1] = c1;
        unsigned* BH32 = (unsigned*)smemA;             // [256][16] u32 (block-swizzled)
        unsigned* BL32 = (unsigned*)(smemA + 16384);
        #pragma unroll
        for (int n2 = 0; n2 < 16; ++n2) {
            float f0 = cf[2*n2], f1 = cf[2*n2+1];
            ushort_t h0 = bf16bits(f0), h1 = bf16bits(f1);
            ushort_t l0 = bf16bits(f0 - bf16val(h0)), l1 = bf16bits(f1 - bf16val(h1));
            int idx = t*16 + ((n2 >> 2) ^ (t & 3))*4 + (n2 & 3);
            BH32[idx] = (unsigned)h0 | ((unsigned)h1 << 16);
            BL32[idx] = (unsigned)l0 | ((unsigned)l1 << 16);
        }
    } else {
        int e = (t - 256) * 8;           // 256 threads x 8 ushorts = 2048
        int r = e >> 6, c = e & 63;
        uint4 vh = *(const uint4*)(PQhi + e);
        uint4 vl = *(const uint4*)(PQlo + e);
        *(uint4*)(PQHs + r*72 + c) = vh;
        *(uint4*)(PQLs + r*72 + c) = vl;
    }
    __syncthreads();

    // ---- stage 0b: y = Phi @ Bfull via MFMA (hi/lo 3-product), write Ay [64 p][264] bf16 ----
    ushort_t* Ay = (ushort_t*)smemA;
    {
        bf16x8 bH[2], bL[2];
        const ushort_t* BHu = (const ushort_t*)smemA;
        const ushort_t* BLu = (const ushort_t*)(smemA + 16384);
        #pragma unroll
        for (int j = 0; j < 2; ++j) {
            const int d = w*32 + j*16 + fr;
            const int off = d*32 + (quad ^ (d & 3))*8;
            bH[j] = *(const bf16x8*)(BHu + off);
            bL[j] = *(const bf16x8*)(BLu + off);
        }
        bf16x8 aH[4], aL[4];
        #pragma unroll
        for (int i = 0; i < 4; ++i) {
            aH[i] = *(const bf16x8*)(phiH + (i*16 + fr)*32 + quad*8);
            aL[i] = *(const bf16x8*)(phiL + (i*16 + fr)*32 + quad*8);
        }
        __syncthreads();   // all BfT reads done before Ay overwrite
        f32x4 accY[4][2];
        #pragma unroll
        for (int i = 0; i < 4; ++i)
            #pragma unroll
            for (int j = 0; j < 2; ++j) {
                f32x4 a = (f32x4){0.f,0.f,0.f,0.f};
                a = __builtin_amdgcn_mfma_f32_16x16x32_bf16(aH[i], bH[j], a, 0, 0, 0);
                a = __builtin_amdgcn_mfma_f32_16x16x32_bf16(aH[i], bL[j], a, 0, 0, 0);
                a = __builtin_amdgcn_mfma_f32_16x16x32_bf16(aL[i], bH[j], a, 0, 0, 0);
                accY[i][j] = a;
            }
        #pragma unroll
        for (int i = 0; i < 4; ++i)
            #pragma unroll
            for (int j = 0; j < 2; ++j)
                #pragma unroll
                for (int r = 0; r < 4; ++r) {
                    const int p = i*16 + quad*4 + r;
                    const int d = w*32 + j*16 + fr;
                    Ay[p*264 + d] = bf16bits(accY[i][j][r]);
                }
    }
    __syncthreads();

    // ---- GEMM1 + tanh + GEMM2 over 4 nh-passes of 128; W2 frags register-prefetched per pass ----
    ushort_t* Hc = (ushort_t*)smemB;     // [64][136]
    f32x4 accF[4][2];                    // rows i*16, d-cols w*32 + j*16
    #pragma unroll
    for (int i = 0; i < 4; ++i)
        #pragma unroll
        for (int j = 0; j < 2; ++j) accF[i][j] = (f32x4){0.f,0.f,0.f,0.f};

    #pragma unroll
    for (int pass = 0; pass < 4; ++pass) {
        // prefetch ALL W2 fragments for this pass; they land during GEMM1's MFMA burst
        bf16x8 w2f[4][2];   // [kt/32][j]
        #pragma unroll
        for (int kt4 = 0; kt4 < 4; ++kt4)
            #pragma unroll
            for (int j = 0; j < 2; ++j) {
                const int d = w*32 + j*16 + fr;
                w2f[kt4][j] = *(const bf16x8*)(W2t + (size_t)d*NHID + pass*128 + kt4*32 + quad*8);
            }
        // GEMM1: acc1 = y(64x256) @ W1 chunk (256 x 128); each wave owns 16 h-cols
        f32x4 acc1[4];
        #pragma unroll
        for (int i = 0; i < 4; ++i) acc1[i] = (f32x4){0.f,0.f,0.f,0.f};
        #pragma unroll
        for (int kt = 0; kt < NDIM; kt += 32) {
            bf16x8 af[4], bfv;
            #pragma unroll
            for (int i = 0; i < 4; ++i)
                af[i] = *(const bf16x8*)(Ay + (i*16 + fr)*264 + kt + quad*8);
            {
                const int ncol = pass*128 + w*16 + fr;
                bfv = *(const bf16x8*)(W1t + (size_t)ncol*NDIM + kt + quad*8);
            }
            #pragma unroll
            for (int i = 0; i < 4; ++i)
                acc1[i] = __builtin_amdgcn_mfma_f32_16x16x32_bf16(af[i], bfv, acc1[i], 0, 0, 0);
        }
        __syncthreads();   // prev pass GEMM2 Hc reads done (also drains w2f loads)
        {
            const int col = w*16 + fr;
            const float bv = b1f[pass*128 + col];
            #pragma unroll
            for (int i = 0; i < 4; ++i)
                #pragma unroll
                for (int r = 0; r < 4; ++r) {
                    const int row = i*16 + quad*4 + r;   // = p, 0..63
                    float v = acc1[i][r] + bv + tchS[row];
                    v = fminf(fmaxf(v, -15.f), 15.f);
                    float e = __expf(2.f*v);
                    Hc[row*136 + col] = bf16bits((e - 1.f)/(e + 1.f));
                }
        }
        __syncthreads();
        // GEMM2 partial: accF += Hc(64x128) @ W2 chunk (128 x 256) — no global loads here
        #pragma unroll
        for (int kt4 = 0; kt4 < 4; ++kt4) {
            bf16x8 af[4];
            #pragma unroll
            for (int i = 0; i < 4; ++i)
                af[i] = *(const bf16x8*)(Hc + (i*16 + fr)*136 + kt4*32 + quad*8);
            #pragma unroll
            for (int i = 0; i < 4; ++i)
                #pragma unroll
                for (int j = 0; j < 2; ++j)
                    accF[i][j] = __builtin_amdgcn_mfma_f32_16x16x32_bf16(af[i], w2f[kt4][j], accF[i][j], 0, 0, 0);
        }
    }
    __syncthreads();   // last GEMM1's Ay reads done; smemA reusable

    // ---- F (+b2) -> FsT [256 d][33] u32 (bf16 row-pairs) ----
    {
        unsigned* FsT32 = (unsigned*)smemA;
        #pragma unroll
        for (int i = 0; i < 4; ++i)
            #pragma unroll
            for (int j = 0; j < 2; ++j) {
                const int d = w*32 + j*16 + fr;
                const float bv = b2f[d];
                #pragma unroll
                for (int rp = 0; rp < 2; ++rp) {
                    unsigned u0 = bf16bits(accF[i][j][rp*2]   + bv);
                    unsigned u1 = bf16bits(accF[i][j][rp*2+1] + bv);
                    FsT32[d*33 + i*8 + quad*2 + rp] = u0 | (u1 << 16);
                }
            }
    }
    __syncthreads();

    // ---- PQ contraction: B_new[n][d] = sum_p PQ[n][p]*F[p][d] - yM2(recon), update Bt + norm ----
    double ss = 0.0;
    {
        const ushort_t* FsTu = (const ushort_t*)smemA;
        // prefetch yv,f for this thread's two d-columns (L2-hot, 1 MB tensor)
        float yvv[2], ffv[2];
        #pragma unroll
        for (int j2 = 0; j2 < 2; ++j2) {
            const int d2 = w*32 + j2*16 + fr;
            yvv[j2] = yfr[((size_t)b*2 + 0)*NDIM + d2];
            ffv[j2] = yfr[((size_t)b*2 + 1)*NDIM + d2];
        }
        f32x4 acc2[2][2];
        #pragma unroll
        for (int m2 = 0; m2 < 2; ++m2)
            #pragma unroll
            for (int j2 = 0; j2 < 2; ++j2) acc2[m2][j2] = (f32x4){0.f,0.f,0.f,0.f};
        #pragma unroll
        for (int kk = 0; kk < 2; ++kk) {
            bf16x8 ah[2], al[2];
            #pragma unroll
            for (int m2 = 0; m2 < 2; ++m2) {
                const int off = (m2*16 + fr)*72 + kk*32 + quad*8;
                ah[m2] = *(const bf16x8*)(PQHs + off);
                al[m2] = *(const bf16x8*)(PQLs + off);
            }
            #pragma unroll
            for (int j2 = 0; j2 < 2; ++j2) {
                const int d2 = w*32 + j2*16 + fr;
                bf16x8 bfv = *(const bf16x8*)(FsTu + d2*66 + kk*32 + quad*8);
                #pragma unroll
                for (int m2 = 0; m2 < 2; ++m2) {
                    acc2[m2][j2] = __builtin_amdgcn_mfma_f32_16x16x32_bf16(ah[m2], bfv, acc2[m2][j2], 0, 0, 0);
                    acc2[m2][j2] = __builtin_amdgcn_mfma_f32_16x16x32_bf16(al[m2], bfv, acc2[m2][j2], 0, 0, 0);
                }
            }
        }
        #pragma unroll
        for (int m2 = 0; m2 < 2; ++m2)
            #pragma unroll
            for (int j2 = 0; j2 < 2; ++j2)
                #pragma unroll
                for (int rr = 0; rr < 4; ++rr) {
                    const int n = m2*16 + quad*4 + rr;
                    if (n < NTAIL) {
                        const int d = w*32 + j2*16 + fr;
                        const size_t idx = ((size_t)b*NTAIL + n)*NDIM + d;
                        float ym2v = yvv[j2]*m2S[n] + ffv[j2]*m2S[32 + n];
                        float val = acc2[m2][j2][rr] - ym2v;
                        float old = Bt[idx];
                        float diff = val - old;
                        Bt[idx] = val;
                        ss += (double)diff*(double)diff;
                    }
                }
    }

    #pragma unroll
    for (int off = 32; off > 0; off >>= 1) ss += __shfl_down(ss, off, 64);
    if (lane == 0) redd[w] = ss;
    __syncthreads();
    if (t == 0) {
        double tot = redd[0] + redd[1] + redd[2] + redd[3]
                   + redd[4] + redd[5] + redd[6] + redd[7];
        atomicAdd(accum, tot);
        __threadfence();
        int old = atomicAdd(counter, 1);
        if (old == 511) {   // last of 512 blocks
            unsigned long long raw = atomicExch((unsigned long long*)accum, 0ull);
            double total; __builtin_memcpy(&total, &raw, 8);
            float dl = (float)sqrt(total);
            *outDelta = dl;
            *counter = 0;
            if (dl < TOLF) *done = 1;
        }
    }
}

// ============ epilogue: traj + B output ============
__global__ __launch_bounds__(256) void kernelEpi(const float* __restrict__ PhiOut, const float* __restrict__ pd2i,
                                                 const float* __restrict__ yf2i, const float* __restrict__ Bt,
                                                 float* __restrict__ outTraj, float* __restrict__ outB)
{
    __shared__ float Po[16][32];
    const int t = threadIdx.x, b = blockIdx.x;
    for (int i = t; i < 512; i += 256) ((float*)Po)[i] = PhiOut[i];
    __syncthreads();
    float cf[32];
    #pragma unroll
    for (int n = 0; n < NTAIL; ++n) cf[2+n] = Bt[((size_t)b*NTAIL + n)*NDIM + t];
    float c0 = yf2i[((size_t)b*2 + 0)*NDIM + t];
    float c1 = yf2i[((size_t)b*2 + 1)*NDIM + t];
    #pragma unroll
    for (int n = 0; n < NTAIL; ++n) { c0 -= cf[2+n]*pd2i[n*2]; c1 -= cf[2+n]*pd2i[n*2+1]; }
    cf[0] = c0; cf[1] = c1;
    for (int tt = 0; tt < TEV; ++tt) {
        float s = 0.f;
        #pragma unroll
        for (int k = 0; k < 32; ++k) s += cf[k]*Po[tt][k];
        outTraj[((size_t)tt*NBATCH + b)*NDIM + t] = s;
    }
    float* ob = outB + ((size_t)(b*NDIM + t))*NTAIL;
    #pragma unroll
    for (int n = 0; n < NTAIL; ++n) ob[n] = cf[2+n];
}

extern "C" void kernel_launch(void* const* d_in, const int* in_sizes, int n_in,
                              void* d_out, int out_size, void* d_ws, size_t ws_size,
                              hipStream_t stream)
{
    const float* y_init = (const float*)d_in[0];
    const float* t_eval = (const float*)d_in[1];
    const float* B_init = (const float*)d_in[2];
    const float* W1     = (const float*)d_in[3];
    const float* b1     = (const float*)d_in[4];
    const float* W2     = (const float*)d_in[5];
    const float* b2     = (const float*)d_in[6];
    float* out = (float*)d_out;
    float* ws  = (float*)d_ws;
    if (ws_size < WS_FLOATS * sizeof(float)) return;

    float* tcheb = ws + OFF_TCHEB;
    float* pd2i  = ws + OFF_PD2I;
    float* M2    = ws + OFF_M2;
    float* inv0  = ws + OFF_INV0;
    float* PhiOut= ws + OFF_PHIOUT;
    double* accum = (double*)(ws + OFF_SCAL);
    int* done    = (int*)(ws + OFF_SCAL + 2);
    int* counter = (int*)(ws + OFF_SCAL + 3);
    float* h1   = ws + OFF_H1F;
    float* yf2i = ws + OFF_YF2I;
    float* yfr  = ws + OFF_YFR;
    float* Bt   = ws + OFF_BT;
    bf16_t* W1t = (bf16_t*)(ws + OFF_W1T);
    bf16_t* W2t = (bf16_t*)(ws + OFF_W2T);
    ushort_t* pqh = (ushort_t*)(ws + OFF_PQBH);
    ushort_t* pql = (ushort_t*)(ws + OFF_PQBL);
    ushort_t* phh = (ushort_t*)(ws + OFF_PHIH);
    ushort_t* phl = (ushort_t*)(ws + OFF_PHIL);

    setup_kernel<<<1, 256, 0, stream>>>(t_eval, ws, out);
    transB_kernel<<<NBATCH, 256, 0, stream>>>(B_init, Bt);
    transW_kernel<<<dim3(NDIM/64, NHID/64), 256, 0, stream>>>(W1, W1t, NDIM, NHID);
    transW_kernel<<<dim3(NHID/64, NDIM/64), 256, 0, stream>>>(W2, W2t, NHID, NDIM);
    finit_h_kernel<<<NBATCH, 512, 0, stream>>>(y_init, W1, b1, t_eval, h1);
    finit_rest_kernel<<<NBATCH, 256, 0, stream>>>(y_init, W2, b2, h1, inv0, yf2i, yfr);

    for (int it = 0; it < MAXIT; ++it) {
        iter_kernel<<<NBATCH, 512, 0, stream>>>(pd2i, yf2i, tcheb, W1t, W2t, b1, b2,
                                                pqh, pql, phh, phl, yfr, M2, Bt,
                                                accum, counter, done, out + OUT_DELTA);
    }
    kernelEpi<<<NBATCH, 256, 0, stream>>>(PhiOut, pd2i, yf2i, Bt, out + OUT_TRAJ, out + OUT_B);
}

// Round 8
// 666.792 us; speedup vs baseline: 3.2123x; 1.0576x over previous
//
#include <hip/hip_runtime.h>
#include <math.h>

#define NBATCH 512
#define NDIM 256
#define NHID 512
#define NC 32
#define NTAIL 30
#define NP 64
#define TEV 16
#define MAXIT 10
#define TOLF 0.01f
#define PI_F 3.14159265358979323846f

typedef __bf16 bf16_t;
typedef __bf16 bf16x8 __attribute__((ext_vector_type(8)));
typedef float f32x4 __attribute__((ext_vector_type(4)));
typedef unsigned short ushort_t;

// ---- workspace layout (float slots) ----
constexpr size_t OFF_TCHEB = 0;        // 64
constexpr size_t OFF_PHIT  = 64;       // 2048
constexpr size_t OFF_PD2I  = 2112;     // 64
constexpr size_t OFF_M2    = 2176;     // 64
constexpr size_t OFF_INV0  = 2240;     // 16 (unused since r8; kept for layout stability)
constexpr size_t OFF_PHIOUT= 2256;     // 512
constexpr size_t OFF_PQ    = 2768;     // 2048 (setup scratch)
constexpr size_t OFF_PQBH  = 4816;     // [32][64] bf16 hi (1024 floats)
constexpr size_t OFF_PQBL  = 5840;     // 1024
constexpr size_t OFF_PHIH  = 6864;     // [64][32] bf16 hi of Phi (A-layout), 1024 floats
constexpr size_t OFF_PHIL  = 7888;     // 1024
constexpr size_t OFF_SCAL  = 8912;     // accum double [0:1], done [2], counter [3]
constexpr size_t OFF_H1F   = 8928;     // (unused since r8 fusion; kept for layout stability)
constexpr size_t OFF_YF2I  = OFF_H1F + 262144;
constexpr size_t OFF_YFR   = OFF_YF2I + 262144;   // [512][2][256] raw yv,f (rank-2 yM2 replacement)
constexpr size_t OFF_BT    = OFF_YFR + 3932160;
constexpr size_t OFF_W1T   = OFF_BT + 3932160;    // [512][256] bf16
constexpr size_t OFF_W2T   = OFF_W1T + 65536;     // [256][512] bf16
constexpr size_t WS_FLOATS = OFF_W2T + 65536;

// ---- output layout (floats) ----
constexpr size_t OUT_TEVAL = 0;
constexpr size_t OUT_TRAJ  = 16;
constexpr size_t OUT_DELTA = 16 + (size_t)TEV*NBATCH*NDIM;
constexpr size_t OUT_B     = OUT_DELTA + 1;

__device__ __forceinline__ ushort_t bf16bits(float v) {
    bf16_t h = (bf16_t)v; ushort_t u; __builtin_memcpy(&u, &h, 2); return u;
}
__device__ __forceinline__ float bf16val(ushort_t u) {
    bf16_t h; __builtin_memcpy(&h, &u, 2); return (float)h;
}

// ============ fused prologue: ONE dispatch replaces setup/transB/transW x2/finit x2 ============
// Round-14: the six prologue kernels were serial dispatches, several nearly
// idle (setup = 1 block on 256 CUs). All are independent given that finit's
// inv0 (2x2 inverse, depends only on t_eval) is recomputed inline with the
// EXACT double-precision sequence setup used (a=1,b=0,c=-sgn,d=sc -> bit-
// identical). Role switch on blockIdx:
//   0            : spectral setup (fp64 parallel GJ, proven round-2/6 body)
//   1..512       : fused f_init  (h -> LDS -> f; no h1 global round-trip)
//   513..1024    : transB (B_init [b][d][n] -> Bt [b][n][d])
//   1025..1056   : transW W1 -> W1t (bf16, transposed)
//   1057..1088   : transW W2 -> W2t
// Shared memory overlaid in one 40KB buffer (setup's GJ arrays are the max).
__global__ __launch_bounds__(512) void prologue_kernel(
    const float* __restrict__ t_eval, const float* __restrict__ y,
    const float* __restrict__ Bin,
    const float* __restrict__ W1, const float* __restrict__ b1,
    const float* __restrict__ W2, const float* __restrict__ b2,
    float* __restrict__ ws, float* __restrict__ out)
{
    struct SetupSh {
        double Gaug[30][61];
        double rowk[60];
        double colk[30];
        float Phi[32][64];
        float DPhi[32][64];
        float Phib[30][64];
        float tcs[64];
        float DtS[64];
        float inv0s[4];
        float pd2s[30][2];
    };
    __shared__ __align__(16) char pm[40960];
    static_assert(sizeof(SetupSh) <= 40960, "SetupSh too big");

    const int tid = threadIdx.x;
    const int role = blockIdx.x;

    if (role == 0) {
        // ---------------- spectral setup ----------------
        SetupSh& S = *(SetupSh*)pm;
        const float t0 = t_eval[0], t1 = t_eval[TEV-1];
        const float sgn = (t1 > t0) ? 1.f : -1.f;

        if (tid < 64) {
            const float t = -sgn * cosf(PI_F * (float)tid / 64.f);
            S.tcs[tid] = t;
            float p0 = 1.f, p1 = t;
            S.Phi[0][tid] = p0; S.Phi[1][tid] = p1;
            for (int k = 2; k < 32; ++k) { float pk = 2.f*t*p1 - p0; S.Phi[k][tid] = pk; p0 = p1; p1 = pk; }
            const float sc = 2.f / (t1 - t0);
            float u0 = 1.f, u1 = 2.f*t;
            S.DPhi[0][tid] = 0.f;
            S.DPhi[1][tid] = sc * 1.f * u0;
            S.DPhi[2][tid] = sc * 2.f * u1;
            for (int k = 3; k < 32; ++k) { float uk = 2.f*t*u1 - u0; S.DPhi[k][tid] = sc * (float)k * uk; u0 = u1; u1 = uk; }
        }
        __syncthreads();
        if (tid < 64) S.DtS[tid] = ((tid < 63) ? S.tcs[tid+1] : 1.0f) - S.tcs[tid];
        if (tid == 0) {
            double a = S.Phi[0][0], b = S.DPhi[0][0], c = S.Phi[1][0], d = S.DPhi[1][0];
            double det = a*d - b*c;
            S.inv0s[0] = (float)( d/det); S.inv0s[1] = (float)(-b/det);
            S.inv0s[2] = (float)(-c/det); S.inv0s[3] = (float)( a/det);
        }
        __syncthreads();
        if (tid < 30) {
            float P = S.Phi[2+tid][0], D = S.DPhi[2+tid][0];
            float a0 = P*S.inv0s[0] + D*S.inv0s[2];
            float a1 = P*S.inv0s[1] + D*S.inv0s[3];
            S.pd2s[tid][0] = a0; S.pd2s[tid][1] = a1;
            ws[OFF_PD2I + tid*2+0] = a0;
            ws[OFF_PD2I + tid*2+1] = a1;
        }
        __syncthreads();
        if (tid < 64)
            for (int m = 0; m < 30; ++m)
                S.Phib[m][tid] = S.DPhi[2+m][tid] - (S.pd2s[m][0]*S.DPhi[0][tid] + S.pd2s[m][1]*S.DPhi[1][tid]);
        __syncthreads();

        for (int e = tid; e < 900; e += 512) {
            int i = e / 30, j = e % 30;
            double s = 0.0;
            for (int p = 0; p < 64; ++p) s += (double)S.Phib[i][p] * (double)S.DtS[p] * (double)S.Phib[j][p];
            S.Gaug[i][j] = s;
            S.Gaug[i][30+j] = (i == j) ? 1.0 : 0.0;
        }
        __syncthreads();

        for (int k = 0; k < 30; ++k) {
            double invpv = 1.0 / S.Gaug[k][k];
            if (tid < 60) S.rowk[tid] = S.Gaug[k][tid] * invpv;
            if (tid >= 64 && tid < 94) S.colk[tid-64] = S.Gaug[tid-64][k];
            __syncthreads();
            for (int e = tid; e < 1800; e += 512) {
                int i = e / 60, j = e - i*60;
                if (i == k) S.Gaug[i][j] = S.rowk[j];
                else        S.Gaug[i][j] -= S.colk[i] * S.rowk[j];
            }
            __syncthreads();
        }

        if (tid < 64) {
            ushort_t* pqh = (ushort_t*)(ws + OFF_PQBH);
            ushort_t* pql = (ushort_t*)(ws + OFF_PQBL);
            float pqrow[32];
            for (int n = 0; n < 30; ++n) {
                double s = 0.0;
                for (int m = 0; m < 30; ++m) s += (double)S.Phib[m][tid] * S.Gaug[m][30+n];
                pqrow[n] = (float)((double)S.DtS[tid] * s);
            }
            pqrow[30] = 0.f; pqrow[31] = 0.f;
            for (int n = 0; n < 32; ++n) {
                ws[OFF_PQ + (size_t)tid*32 + n] = pqrow[n];
                bf16_t h = (bf16_t)pqrow[n];
                float hf = (float)h;
                pqh[n*64 + tid] = bf16bits(pqrow[n]);
                pql[n*64 + tid] = bf16bits(pqrow[n] - hf);
            }
        }
        __syncthreads();

        if (tid < 30) {
            double a20 = 0.0, a21 = 0.0;
            for (int p = 0; p < 64; ++p) {
                double pq = (double)ws[OFF_PQ + (size_t)p*32 + tid];
                a20 += (double)S.DPhi[0][p] * pq;
                a21 += (double)S.DPhi[1][p] * pq;
            }
            ws[OFF_M2 + 0*32 + tid] = (float)((double)S.inv0s[0]*a20 + (double)S.inv0s[1]*a21);
            ws[OFF_M2 + 1*32 + tid] = (float)((double)S.inv0s[2]*a20 + (double)S.inv0s[3]*a21);
        }

        if (tid < 64) {
            ushort_t* phh = (ushort_t*)(ws + OFF_PHIH);
            ushort_t* phl = (ushort_t*)(ws + OFF_PHIL);
            for (int n = 0; n < 32; ++n) {
                float f = S.Phi[n][tid];
                ws[OFF_PHIT + (size_t)tid*32 + n] = f;
                ushort_t hb = bf16bits(f);
                phh[tid*32 + n] = hb;
                phl[tid*32 + n] = bf16bits(f - bf16val(hb));
            }
            ws[OFF_TCHEB + tid] = S.tcs[tid];
        }

        if (tid < TEV) {
            float te = t_eval[tid];
            out[OUT_TEVAL + tid] = te;
            float tt = -1.f + 2.f*(te - t0)/(t1 - t0);
            float q0 = 1.f, q1 = tt;
            ws[OFF_PHIOUT + (size_t)tid*32 + 0] = q0;
            ws[OFF_PHIOUT + (size_t)tid*32 + 1] = q1;
            for (int k = 2; k < 32; ++k) { float qk = 2.f*tt*q1 - q0; ws[OFF_PHIOUT + (size_t)tid*32 + k] = qk; q0 = q1; q1 = qk; }
        }

        if (tid == 0) {
            double* acc = (double*)(ws + OFF_SCAL);
            acc[0] = 0.0;
            int* ip = (int*)(ws + OFF_SCAL + 2);
            ip[0] = 0;  // done
            ip[1] = 0;  // counter
        }
    } else if (role <= NBATCH) {
        // ---------------- fused f_init (h in LDS, then f) ----------------
        const int b = role - 1;
        float* ys = (float*)pm;          // [256]
        float* hs = (float*)pm + 256;    // [512]
        if (tid < NDIM) ys[tid] = y[(size_t)b*NDIM + tid];
        __syncthreads();
        {
            float acc = b1[tid] + t_eval[0];
            for (int d = 0; d < NDIM; ++d) acc += ys[d] * W1[(size_t)d*NHID + tid];
            hs[tid] = tanhf(acc);
        }
        __syncthreads();
        if (tid < NDIM) {
            float f = b2[tid];
            for (int h = 0; h < NHID; ++h) f += hs[h] * W2[(size_t)h*NDIM + tid];
            const float yv = ys[tid];
            // inline inv0 — EXACT replica of setup's double-precision sequence:
            // Phi[0][0]=1, DPhi[0][0]=0, Phi[1][0]=-sgn (cosf(0)=1), DPhi[1][0]=sc
            const float t0 = t_eval[0], t1 = t_eval[TEV-1];
            const float sgn = (t1 > t0) ? 1.f : -1.f;
            const float sc = 2.f / (t1 - t0);
            double a = 1.0, bb = 0.0, c = (double)(-sgn), d = (double)sc;
            double det = a*d - bb*c;
            const float i0 = (float)( d/det), i1 = (float)(-bb/det);
            const float i2 = (float)(-c/det), i3 = (float)( a/det);
            float* yf2i = ws + OFF_YF2I;
            float* yfr  = ws + OFF_YFR;
            yf2i[((size_t)b*2 + 0)*NDIM + tid] = yv*i0 + f*i2;
            yf2i[((size_t)b*2 + 1)*NDIM + tid] = yv*i1 + f*i3;
            yfr [((size_t)b*2 + 0)*NDIM + tid] = yv;
            yfr [((size_t)b*2 + 1)*NDIM + tid] = f;
        }
    } else if (role <= 2*NBATCH) {
        // ---------------- transB ----------------
        if (tid < NDIM) {
            const int b = role - NBATCH - 1;
            float* Bt = ws + OFF_BT;
            const float* src = Bin + ((size_t)(b*NDIM + tid)) * NTAIL;
            #pragma unroll
            for (int n = 0; n < NTAIL; ++n)
                Bt[((size_t)b*NTAIL + n)*NDIM + tid] = src[n];
        }
    } else {
        // ---------------- transW (W1 then W2 tiles) ----------------
        const bool isW1 = (role <= 2*NBATCH + 32);
        const int idx = isW1 ? (role - 2*NBATCH - 1) : (role - 2*NBATCH - 33);
        const int R = isW1 ? NDIM : NHID;
        const int C = isW1 ? NHID : NDIM;
        const float* W = isW1 ? W1 : W2;
        bf16_t* Wt = (bf16_t*)(ws + (isW1 ? OFF_W1T : OFF_W2T));
        const int nbx = R / 64;
        const int r0 = (idx % nbx) * 64, c0 = (idx / nbx) * 64;
        float (*Ls)[65] = (float(*)[65])pm;
        const int lr = tid >> 6, lc = tid & 63;   // lr 0..7 (512 threads)
        #pragma unroll
        for (int i = 0; i < 8; ++i) {
            int rr = i*8 + lr;
            Ls[rr][lc] = W[(size_t)(r0+rr)*C + c0+lc];
        }
        __syncthreads();
        #pragma unroll
        for (int i = 0; i < 8; ++i) {
            int cc = i*8 + lr;
            Wt[(size_t)(c0+cc)*R + r0 + lc] = (bf16_t)Ls[lc][cc];
        }
    }
}

// ============ fused iteration kernel (r7 body, UNCHANGED — proven 59-61 µs) ============
// 512 blocks x 512 threads (8 waves), 2 blocks/CU -> 16 waves/CU.
// NOTE (r5): never cooperative/persistent — grid.sync() on gfx950 forces
// cross-XCD L2 writeback (9x HBM). NOTE (r6): 1024 threads spills (VGPR cap
// 64 at 8 waves/SIMD). NOTE (r3/r4): superpass & barrier-merge both regress.
__global__ __launch_bounds__(512, 4) void iter_kernel(
    const float* __restrict__ pd2i, const float* __restrict__ yf2i, const float* __restrict__ tch,
    const bf16_t* __restrict__ W1t, const bf16_t* __restrict__ W2t,
    const float* __restrict__ b1f, const float* __restrict__ b2f,
    const ushort_t* __restrict__ PQhi, const ushort_t* __restrict__ PQlo,
    const ushort_t* __restrict__ phiH, const ushort_t* __restrict__ phiL,
    const float* __restrict__ yfr, const float* __restrict__ M2f,
    float* __restrict__ Bt,
    double* __restrict__ accum, int* __restrict__ counter,
    int* __restrict__ done, float* __restrict__ outDelta)
{
    if (*done) return;
    __shared__ float pd2s[32][2];
    __shared__ float tchS[64];
    __shared__ float m2S[64];
    __shared__ double redd[8];
    __shared__ __align__(16) char smemA[33792];  // BfT hi/lo -> Ay [64][264]us -> FsT [256][33]u32
    __shared__ __align__(16) char smemB[17408];  // Hc [64][136]us
    __shared__ __align__(16) ushort_t PQHs[32*72];
    __shared__ __align__(16) ushort_t PQLs[32*72];

    const int t = threadIdx.x;
    const int b = blockIdx.x;            // batch index 0..511
    const int lane = t & 63, w = t >> 6;             // w 0..7
    const int fr = lane & 15, quad = lane >> 4;

    // ---- tiny constants into LDS (pd2s needed immediately by 0a) ----
    if (t < 60) ((float*)pd2s)[t] = pd2i[t];
    if (t >= 64 && t < 128) tchS[t-64] = tch[t-64];
    if (t >= 128 && t < 192) m2S[t-128] = M2f[t-128];
    __syncthreads();

    // ---- stage 0a (threads 0..255) CONCURRENT with PQ staging (threads 256..511) ----
    if (t < 256) {
        float cf[32];
        #pragma unroll
        for (int n = 0; n < NTAIL; ++n) cf[2+n] = Bt[((size_t)b*NTAIL + n)*NDIM + t];
        float c0 = yf2i[((size_t)b*2 + 0)*NDIM + t];
        float c1 = yf2i[((size_t)b*2 + 1)*NDIM + t];
        #pragma unroll
        for (int n = 0; n < NTAIL; ++n) { c0 -= cf[2+n]*pd2s[n][0]; c1 -= cf[2+n]*pd2s[n][1]; }
        cf[0] = c0; cf[1] = c1;
        unsigned* BH32 = (unsigned*)smemA;             // [256][16] u32 (block-swizzled)
        unsigned* BL32 = (unsigned*)(smemA + 16384);
        #pragma unroll
        for (int n2 = 0; n2 < 16; ++n2) {
            float f0 = cf[2*n2], f1 = cf[2*n2+1];
            ushort_t h0 = bf16bits(f0), h1 = bf16bits(f1);
            ushort_t l0 = bf16bits(f0 - bf16val(h0)), l1 = bf16bits(f1 - bf16val(h1));
            int idx = t*16 + ((n2 >> 2) ^ (t & 3))*4 + (n2 & 3);
            BH32[idx] = (unsigned)h0 | ((unsigned)h1 << 16);
            BL32[idx] = (unsigned)l0 | ((unsigned)l1 << 16);
        }
    } else {
        int e = (t - 256) * 8;           // 256 threads x 8 ushorts = 2048
        int r = e >> 6, c = e & 63;
        uint4 vh = *(const uint4*)(PQhi + e);
        uint4 vl = *(const uint4*)(PQlo + e);
        *(uint4*)(PQHs + r*72 + c) = vh;
        *(uint4*)(PQLs + r*72 + c) = vl;
    }
    __syncthreads();

    // ---- stage 0b: y = Phi @ Bfull via MFMA (hi/lo 3-product), write Ay [64 p][264] bf16 ----
    ushort_t* Ay = (ushort_t*)smemA;
    {
        bf16x8 bH[2], bL[2];
        const ushort_t* BHu = (const ushort_t*)smemA;
        const ushort_t* BLu = (const ushort_t*)(smemA + 16384);
        #pragma unroll
        for (int j = 0; j < 2; ++j) {
            const int d = w*32 + j*16 + fr;
            const int off = d*32 + (quad ^ (d & 3))*8;
            bH[j] = *(const bf16x8*)(BHu + off);
            bL[j] = *(const bf16x8*)(BLu + off);
        }
        bf16x8 aH[4], aL[4];
        #pragma unroll
        for (int i = 0; i < 4; ++i) {
            aH[i] = *(const bf16x8*)(phiH + (i*16 + fr)*32 + quad*8);
            aL[i] = *(const bf16x8*)(phiL + (i*16 + fr)*32 + quad*8);
        }
        __syncthreads();   // all BfT reads done before Ay overwrite
        f32x4 accY[4][2];
        #pragma unroll
        for (int i = 0; i < 4; ++i)
            #pragma unroll
            for (int j = 0; j < 2; ++j) {
                f32x4 a = (f32x4){0.f,0.f,0.f,0.f};
                a = __builtin_amdgcn_mfma_f32_16x16x32_bf16(aH[i], bH[j], a, 0, 0, 0);
                a = __builtin_amdgcn_mfma_f32_16x16x32_bf16(aH[i], bL[j], a, 0, 0, 0);
                a = __builtin_amdgcn_mfma_f32_16x16x32_bf16(aL[i], bH[j], a, 0, 0, 0);
                accY[i][j] = a;
            }
        #pragma unroll
        for (int i = 0; i < 4; ++i)
            #pragma unroll
            for (int j = 0; j < 2; ++j)
                #pragma unroll
                for (int r = 0; r < 4; ++r) {
                    const int p = i*16 + quad*4 + r;
                    const int d = w*32 + j*16 + fr;
                    Ay[p*264 + d] = bf16bits(accY[i][j][r]);
                }
    }
    __syncthreads();

    // ---- GEMM1 + tanh + GEMM2 over 4 nh-passes of 128; W2 frags register-prefetched per pass ----
    ushort_t* Hc = (ushort_t*)smemB;     // [64][136]
    f32x4 accF[4][2];                    // rows i*16, d-cols w*32 + j*16
    #pragma unroll
    for (int i = 0; i < 4; ++i)
        #pragma unroll
        for (int j = 0; j < 2; ++j) accF[i][j] = (f32x4){0.f,0.f,0.f,0.f};

    #pragma unroll
    for (int pass = 0; pass < 4; ++pass) {
        // prefetch ALL W2 fragments for this pass; they land during GEMM1's MFMA burst
        bf16x8 w2f[4][2];   // [kt/32][j]
        #pragma unroll
        for (int kt4 = 0; kt4 < 4; ++kt4)
            #pragma unroll
            for (int j = 0; j < 2; ++j) {
                const int d = w*32 + j*16 + fr;
                w2f[kt4][j] = *(const bf16x8*)(W2t + (size_t)d*NHID + pass*128 + kt4*32 + quad*8);
            }
        // GEMM1: acc1 = y(64x256) @ W1 chunk (256 x 128); each wave owns 16 h-cols
        f32x4 acc1[4];
        #pragma unroll
        for (int i = 0; i < 4; ++i) acc1[i] = (f32x4){0.f,0.f,0.f,0.f};
        #pragma unroll
        for (int kt = 0; kt < NDIM; kt += 32) {
            bf16x8 af[4], bfv;
            #pragma unroll
            for (int i = 0; i < 4; ++i)
                af[i] = *(const bf16x8*)(Ay + (i*16 + fr)*264 + kt + quad*8);
            {
                const int ncol = pass*128 + w*16 + fr;
                bfv = *(const bf16x8*)(W1t + (size_t)ncol*NDIM + kt + quad*8);
            }
            #pragma unroll
            for (int i = 0; i < 4; ++i)
                acc1[i] = __builtin_amdgcn_mfma_f32_16x16x32_bf16(af[i], bfv, acc1[i], 0, 0, 0);
        }
        __syncthreads();   // prev pass GEMM2 Hc reads done (also drains w2f loads)
        {
            const int col = w*16 + fr;
            const float bv = b1f[pass*128 + col];
            #pragma unroll
            for (int i = 0; i < 4; ++i)
                #pragma unroll
                for (int r = 0; r < 4; ++r) {
                    const int row = i*16 + quad*4 + r;   // = p, 0..63
                    float v = acc1[i][r] + bv + tchS[row];
                    v = fminf(fmaxf(v, -15.f), 15.f);
                    float e = __expf(2.f*v);
                    Hc[row*136 + col] = bf16bits((e - 1.f)/(e + 1.f));
                }
        }
        __syncthreads();
        // GEMM2 partial: accF += Hc(64x128) @ W2 chunk (128 x 256) — no global loads here
        #pragma unroll
        for (int kt4 = 0; kt4 < 4; ++kt4) {
            bf16x8 af[4];
            #pragma unroll
            for (int i = 0; i < 4; ++i)
                af[i] = *(const bf16x8*)(Hc + (i*16 + fr)*136 + kt4*32 + quad*8);
            #pragma unroll
            for (int i = 0; i < 4; ++i)
                #pragma unroll
                for (int j = 0; j < 2; ++j)
                    accF[i][j] = __builtin_amdgcn_mfma_f32_16x16x32_bf16(af[i], w2f[kt4][j], accF[i][j], 0, 0, 0);
        }
    }
    __syncthreads();   // last GEMM1's Ay reads done; smemA reusable

    // ---- F (+b2) -> FsT [256 d][33] u32 (bf16 row-pairs) ----
    {
        unsigned* FsT32 = (unsigned*)smemA;
        #pragma unroll
        for (int i = 0; i < 4; ++i)
            #pragma unroll
            for (int j = 0; j < 2; ++j) {
                const int d = w*32 + j*16 + fr;
                const float bv = b2f[d];
                #pragma unroll
                for (int rp = 0; rp < 2; ++rp) {
                    unsigned u0 = bf16bits(accF[i][j][rp*2]   + bv);
                    unsigned u1 = bf16bits(accF[i][j][rp*2+1] + bv);
                    FsT32[d*33 + i*8 + quad*2 + rp] = u0 | (u1 << 16);
                }
            }
    }
    __syncthreads();

    // ---- PQ contraction: B_new[n][d] = sum_p PQ[n][p]*F[p][d] - yM2(recon), update Bt + norm ----
    double ss = 0.0;
    {
        const ushort_t* FsTu = (const ushort_t*)smemA;
        // prefetch yv,f for this thread's two d-columns (L2-hot, 1 MB tensor)
        float yvv[2], ffv[2];
        #pragma unroll
        for (int j2 = 0; j2 < 2; ++j2) {
            const int d2 = w*32 + j2*16 + fr;
            yvv[j2] = yfr[((size_t)b*2 + 0)*NDIM + d2];
            ffv[j2] = yfr[((size_t)b*2 + 1)*NDIM + d2];
        }
        f32x4 acc2[2][2];
        #pragma unroll
        for (int m2 = 0; m2 < 2; ++m2)
            #pragma unroll
            for (int j2 = 0; j2 < 2; ++j2) acc2[m2][j2] = (f32x4){0.f,0.f,0.f,0.f};
        #pragma unroll
        for (int kk = 0; kk < 2; ++kk) {
            bf16x8 ah[2], al[2];
            #pragma unroll
            for (int m2 = 0; m2 < 2; ++m2) {
                const int off = (m2*16 + fr)*72 + kk*32 + quad*8;
                ah[m2] = *(const bf16x8*)(PQHs + off);
                al[m2] = *(const bf16x8*)(PQLs + off);
            }
            #pragma unroll
            for (int j2 = 0; j2 < 2; ++j2) {
                const int d2 = w*32 + j2*16 + fr;
                bf16x8 bfv = *(const bf16x8*)(FsTu + d2*66 + kk*32 + quad*8);
                #pragma unroll
                for (int m2 = 0; m2 < 2; ++m2) {
                    acc2[m2][j2] = __builtin_amdgcn_mfma_f32_16x16x32_bf16(ah[m2], bfv, acc2[m2][j2], 0, 0, 0);
                    acc2[m2][j2] = __builtin_amdgcn_mfma_f32_16x16x32_bf16(al[m2], bfv, acc2[m2][j2], 0, 0, 0);
                }
            }
        }
        #pragma unroll
        for (int m2 = 0; m2 < 2; ++m2)
            #pragma unroll
            for (int j2 = 0; j2 < 2; ++j2)
                #pragma unroll
                for (int rr = 0; rr < 4; ++rr) {
                    const int n = m2*16 + quad*4 + rr;
                    if (n < NTAIL) {
                        const int d = w*32 + j2*16 + fr;
                        const size_t idx = ((size_t)b*NTAIL + n)*NDIM + d;
                        float ym2v = yvv[j2]*m2S[n] + ffv[j2]*m2S[32 + n];
                        float val = acc2[m2][j2][rr] - ym2v;
                        float old = Bt[idx];
                        float diff = val - old;
                        Bt[idx] = val;
                        ss += (double)diff*(double)diff;
                    }
                }
    }

    #pragma unroll
    for (int off = 32; off > 0; off >>= 1) ss += __shfl_down(ss, off, 64);
    if (lane == 0) redd[w] = ss;
    __syncthreads();
    if (t == 0) {
        double tot = redd[0] + redd[1] + redd[2] + redd[3]
                   + redd[4] + redd[5] + redd[6] + redd[7];
        atomicAdd(accum, tot);
        __threadfence();
        int old = atomicAdd(counter, 1);
        if (old == 511) {   // last of 512 blocks
            unsigned long long raw = atomicExch((unsigned long long*)accum, 0ull);
            double total; __builtin_memcpy(&total, &raw, 8);
            float dl = (float)sqrt(total);
            *outDelta = dl;
            *counter = 0;
            if (dl < TOLF) *done = 1;
        }
    }
}

// ============ epilogue: traj + B output ============
__global__ __launch_bounds__(256) void kernelEpi(const float* __restrict__ PhiOut, const float* __restrict__ pd2i,
                                                 const float* __restrict__ yf2i, const float* __restrict__ Bt,
                                                 float* __restrict__ outTraj, float* __restrict__ outB)
{
    __shared__ float Po[16][32];
    const int t = threadIdx.x, b = blockIdx.x;
    for (int i = t; i < 512; i += 256) ((float*)Po)[i] = PhiOut[i];
    __syncthreads();
    float cf[32];
    #pragma unroll
    for (int n = 0; n < NTAIL; ++n) cf[2+n] = Bt[((size_t)b*NTAIL + n)*NDIM + t];
    float c0 = yf2i[((size_t)b*2 + 0)*NDIM + t];
    float c1 = yf2i[((size_t)b*2 + 1)*NDIM + t];
    #pragma unroll
    for (int n = 0; n < NTAIL; ++n) { c0 -= cf[2+n]*pd2i[n*2]; c1 -= cf[2+n]*pd2i[n*2+1]; }
    cf[0] = c0; cf[1] = c1;
    for (int tt = 0; tt < TEV; ++tt) {
        float s = 0.f;
        #pragma unroll
        for (int k = 0; k < 32; ++k) s += cf[k]*Po[tt][k];
        outTraj[((size_t)tt*NBATCH + b)*NDIM + t] = s;
    }
    float* ob = outB + ((size_t)(b*NDIM + t))*NTAIL;
    #pragma unroll
    for (int n = 0; n < NTAIL; ++n) ob[n] = cf[2+n];
}

extern "C" void kernel_launch(void* const* d_in, const int* in_sizes, int n_in,
                              void* d_out, int out_size, void* d_ws, size_t ws_size,
                              hipStream_t stream)
{
    const float* y_init = (const float*)d_in[0];
    const float* t_eval = (const float*)d_in[1];
    const float* B_init = (const float*)d_in[2];
    const float* W1     = (const float*)d_in[3];
    const float* b1     = (const float*)d_in[4];
    const float* W2     = (const float*)d_in[5];
    const float* b2     = (const float*)d_in[6];
    float* out = (float*)d_out;
    float* ws  = (float*)d_ws;
    if (ws_size < WS_FLOATS * sizeof(float)) return;

    float* tcheb = ws + OFF_TCHEB;
    float* pd2i  = ws + OFF_PD2I;
    float* M2    = ws + OFF_M2;
    float* PhiOut= ws + OFF_PHIOUT;
    double* accum = (double*)(ws + OFF_SCAL);
    int* done    = (int*)(ws + OFF_SCAL + 2);
    int* counter = (int*)(ws + OFF_SCAL + 3);
    float* yf2i = ws + OFF_YF2I;
    float* yfr  = ws + OFF_YFR;
    float* Bt   = ws + OFF_BT;
    bf16_t* W1t = (bf16_t*)(ws + OFF_W1T);
    bf16_t* W2t = (bf16_t*)(ws + OFF_W2T);
    ushort_t* pqh = (ushort_t*)(ws + OFF_PQBH);
    ushort_t* pql = (ushort_t*)(ws + OFF_PQBL);
    ushort_t* phh = (ushort_t*)(ws + OFF_PHIH);
    ushort_t* phl = (ushort_t*)(ws + OFF_PHIL);

    // one fused prologue dispatch: setup + finit + transB + transW x2
    prologue_kernel<<<1 + 2*NBATCH + 64, 512, 0, stream>>>(
        t_eval, y_init, B_init, W1, b1, W2, b2, ws, out);

    for (int it = 0; it < MAXIT; ++it) {
        iter_kernel<<<NBATCH, 512, 0, stream>>>(pd2i, yf2i, tcheb, W1t, W2t, b1, b2,
                                                pqh, pql, phh, phl, yfr, M2, Bt,
                                                accum, counter, done, out + OUT_DELTA);
    }
    kernelEpi<<<NBATCH, 256, 0, stream>>>(PhiOut, pd2i, yf2i, Bt, out + OUT_TRAJ, out + OUT_B);
}